// Round 3
// baseline (375.365 us; speedup 1.0000x reference)
//
#include <hip/hip_runtime.h>
#include <hip/hip_bf16.h>

// Problem: B=2, S=2048, C=U=1024, H=16, dh=64. I/O FP32.
// 4 dispatches: prep (cast X->bf16 + transpose/cast W->bf16 + zero stats/flags),
// QKV GEMM (m97-style staging; Q pre-scaled; V written directly in [b,h,d,s]),
// flash attention (paired-qtile + kv-split uniform blocks, additive partial
// combine via last-finisher flag, async global_load_lds into XOR-swizzled LDS,
// offset-free exp2 softmax, fused residual+LN-stats), LN apply.

typedef __bf16 bf16_t;
typedef __bf16 bf16x8 __attribute__((ext_vector_type(8)));
typedef __bf16 bf16x4 __attribute__((ext_vector_type(4)));
typedef _Float16 f16_t;
typedef _Float16 f16x2 __attribute__((ext_vector_type(2)));
typedef _Float16 f16x4 __attribute__((ext_vector_type(4)));
typedef _Float16 f16x8 __attribute__((ext_vector_type(8)));
typedef float f32x4 __attribute__((ext_vector_type(4)));

constexpr int Bsz = 2;
constexpr int Seq = 2048;
constexpr int Cdim = 1024;   // == U
constexpr int Udim = 1024;
constexpr int Hn = 16;
constexpr int Dh = 64;
constexpr int Mrows = Bsz * Seq;          // 4096
constexpr int PerBatch = Seq * Udim;      // 2^21
constexpr float SCLQ = 0.125f * 1.44269504088896340736f;  // /sqrt(dh) * log2e

#if __has_builtin(__builtin_amdgcn_exp2f)
#define EXP2F(x) __builtin_amdgcn_exp2f(x)
#else
#define EXP2F(x) exp2f(x)
#endif

#define AINL __attribute__((always_inline))

// async global->LDS, 16B per lane; LDS dest = wave-uniform base + lane*16
__device__ __forceinline__ void gload16(const void* g, void* l)
{
    __builtin_amdgcn_global_load_lds(
        (const __attribute__((address_space(1))) void*)g,
        (__attribute__((address_space(3))) void*)l, 16, 0, 0);
}

// pack two f32 -> f16x2 via v_cvt_pkrtz (returns __fp16x2; bit-identical)
__device__ __forceinline__ f16x2 pkrtz(float a, float b)
{
    return __builtin_bit_cast(f16x2, __builtin_amdgcn_cvt_pkrtz(a, b));
}

// ---------------------------------------------------------------- prep
__global__ __launch_bounds__(256)
void prep(const float* __restrict__ X,
          const float* __restrict__ Wq, const float* __restrict__ Wk,
          const float* __restrict__ Wv,
          bf16_t* __restrict__ Xb,
          bf16_t* __restrict__ Tq, bf16_t* __restrict__ Tk,
          bf16_t* __restrict__ Tv, float* __restrict__ stats,
          int* __restrict__ flags)
{
    int z = blockIdx.z;
    int tid = threadIdx.x;
    if (z < 3) {
        const float* W = (z == 0) ? Wq : (z == 1) ? Wk : Wv;
        bf16_t* T = (z == 0) ? Tq : (z == 1) ? Tk : Tv;
        __shared__ bf16_t t[64][65];
        int x0 = blockIdx.x * 64, y0 = blockIdx.y * 64;
        int tx = tid & 63, ty = tid >> 6;
        for (int i = ty; i < 64; i += 4)
            t[i][tx] = (bf16_t)W[(size_t)(y0 + i) * Cdim + x0 + tx];
        __syncthreads();
        for (int i = ty; i < 64; i += 4)
            T[(size_t)(x0 + i) * Cdim + y0 + tx] = t[tx][i];
    } else {
        int bi = blockIdx.y * 16 + blockIdx.x;          // 0..255
        if (bi == 0) {
            if (tid < 4) stats[tid] = 0.0f;
            flags[tid] = 0;
            flags[tid + 256] = 0;
        }
        const float4* Xv = (const float4*)X;
#pragma unroll
        for (int k = 0; k < 16; k++) {
            int i = bi * 4096 + k * 256 + tid;          // 1M float4 total
            float4 v = Xv[i];
            bf16x4 o = { (bf16_t)v.x, (bf16_t)v.y, (bf16_t)v.z, (bf16_t)v.w };
            *(bf16x4*)(Xb + (size_t)i * 4) = o;
        }
    }
}

// ---------------------------------------------------------------- QKV GEMM
// m97 structure: 128x128 tile, BK=32, unpadded LDS, global_load_lds width 16.
// z==0: Q pre-scaled by SCLQ. z==1: K. z==2: V -> Vt[b][h][d][s].
__global__ __launch_bounds__(256)
void gemm_qkv(const bf16_t* __restrict__ X,
              const bf16_t* __restrict__ Wt0, const bf16_t* __restrict__ Wt1,
              const bf16_t* __restrict__ Wt2,
              const float* __restrict__ b0, const float* __restrict__ b1,
              const float* __restrict__ b2,
              f16_t* __restrict__ O0, f16_t* __restrict__ O1, f16_t* __restrict__ O2v)
{
    int z = blockIdx.z;
    const bf16_t* Wt = (z == 0) ? Wt0 : (z == 1) ? Wt1 : Wt2;
    const float* bias = (z == 0) ? b0 : (z == 1) ? b1 : b2;
    float scl = (z == 0) ? SCLQ : 1.0f;

    constexpr int Kd = 1024, Nd = 1024;
    __shared__ __align__(16) bf16_t As[128 * 32];
    __shared__ __align__(16) bf16_t Bs[128 * 32];

    int tid = threadIdx.x;
    int wave = tid >> 6, lane = tid & 63, quad = lane >> 4, l16 = lane & 15;
    int wm = (wave & 1) * 64, wn = (wave >> 1) * 64;
    int m0 = blockIdx.y * 128, n0 = blockIdx.x * 128;

    f32x4 acc[4][4] = {};

    int e0 = wave * 512 + lane * 8;
    int r0 = e0 >> 5, c0 = e0 & 31;
    int e1 = e0 + 2048;
    int r1 = e1 >> 5, c1 = e1 & 31;
    const bf16_t* Ag = X + (size_t)m0 * Kd;
    const bf16_t* Bg = Wt + (size_t)n0 * Kd;
    bf16_t* AsW0 = As + wave * 512;
    bf16_t* AsW1 = As + 2048 + wave * 512;
    bf16_t* BsW0 = Bs + wave * 512;
    bf16_t* BsW1 = Bs + 2048 + wave * 512;

    for (int k0 = 0; k0 < Kd; k0 += 32) {
        gload16(Ag + (size_t)r0 * Kd + k0 + c0, AsW0);
        gload16(Ag + (size_t)r1 * Kd + k0 + c1, AsW1);
        gload16(Bg + (size_t)r0 * Kd + k0 + c0, BsW0);
        gload16(Bg + (size_t)r1 * Kd + k0 + c1, BsW1);
        __syncthreads();

        bf16x8 af[4], bfr[4];
#pragma unroll
        for (int i = 0; i < 4; i++)
            af[i] = *(const bf16x8*)&As[(wm + i * 16 + l16) * 32 + quad * 8];
#pragma unroll
        for (int i = 0; i < 4; i++)
            bfr[i] = *(const bf16x8*)&Bs[(wn + i * 16 + l16) * 32 + quad * 8];
#pragma unroll
        for (int mt = 0; mt < 4; mt++)
#pragma unroll
            for (int nt = 0; nt < 4; nt++)
                acc[mt][nt] = __builtin_amdgcn_mfma_f32_16x16x32_bf16(
                    af[mt], bfr[nt], acc[mt][nt], 0, 0, 0);
        __syncthreads();
    }

    if (z < 2) {
        f16_t* Og = (z == 0) ? O0 : O1;
#pragma unroll
        for (int nt = 0; nt < 4; nt++) {
            int col = n0 + wn + nt * 16 + l16;
            float bv = bias[col];
#pragma unroll
            for (int mt = 0; mt < 4; mt++) {
                int row = m0 + wm + mt * 16 + quad * 4;
#pragma unroll
                for (int r = 0; r < 4; r++)
                    Og[(size_t)(row + r) * Nd + col] = (f16_t)((acc[mt][nt][r] + bv) * scl);
            }
        }
    } else {
        int bb = m0 >> 11;
#pragma unroll
        for (int nt = 0; nt < 4; nt++) {
            int col = n0 + wn + nt * 16 + l16;
            float bv = bias[col];
            int h = col >> 6, d = col & 63;
            f16_t* vbase = O2v + (((size_t)(bb * Hn + h) * Dh + d) << 11);
#pragma unroll
            for (int mt = 0; mt < 4; mt++) {
                int row = m0 + wm + mt * 16 + quad * 4;
                int s = row & (Seq - 1);
                f16x4 pk;
#pragma unroll
                for (int r = 0; r < 4; r++) pk[r] = (f16_t)(acc[mt][nt][r] + bv);
                *(f16x4*)(vbase + s) = pk;
            }
        }
    }
}

// ---------------------------------------------------------------- attention
// 1024 blocks: pair (qa=31-pi, qb=pi) kv-split at split=15-pi into two
// uniform sub-blocks: sub0 = A over kv[0,split) + all of B (cost 16),
// sub1 = A over kv[split,qa] incl diag (cost 17). Offset-free softmax =>
// partial (O,lsum) combine ADDITIVELY; last-finisher (flag atomicAdd)
// combines A, normalizes, writes residual+stats. 4 blocks/CU resident,
// uniform work => no tail. XOR-swizzled LDS fed by global_load_lds with
// pre-swizzled source. Buffer parity compile-time via parity-peeled runs.
__global__ __launch_bounds__(256, 4)
void attn10(const f16_t* __restrict__ Q, const f16_t* __restrict__ K,
            const f16_t* __restrict__ Vt, const float* __restrict__ X,
            bf16_t* __restrict__ R, float* __restrict__ stats,
            float* __restrict__ POA, float* __restrict__ PLS,
            int* __restrict__ flags)
{
    int id = blockIdx.x;
    int c = id & 7;            // XCD slot; pair-subs differ by 8 -> same XCD
    int r = id >> 3;           // 0..127
    int s = r & 1;             // sub-block within pair
    int rr = r >> 1;           // 0..63
    int g = rr & 3;
    int pi = rr >> 2;          // 0..15 pair index
    int bh = (g << 3) | c;
    int b = bh >> 4, h = bh & 15;
    int qa = 31 - pi;          // heavy qtile
    int qb = pi;               // light qtile
    int split = 15 - pi;       // A kv-tiles [0,split) -> sub0, [split,qa] -> sub1
    int pg = bh * 16 + pi;     // pair slot 0..511

    int tid = threadIdx.x;
    int w = tid >> 6, lane = tid & 63, quad = lane >> 4, l16 = lane & 15;
    size_t bS = (size_t)b * Seq;

    __shared__ __align__(16) f16_t Ks[2][4096];   // [buf][kv][d] swizzled
    __shared__ __align__(16) f16_t Vs[2][4096];   // [buf][d][kv] swizzled
    __shared__ float red[8];
    __shared__ int shOld;

    const f16_t* Kg = K + bS * Udim + h * Dh;
    const f16_t* Vg = Vt + ((size_t)(b * Hn + h)) * Dh * Seq;

    // staging geometry (pre-swizzled global source, rule #21)
    int srow = w * 8 + (lane >> 3);
    int schunk = (lane & 7) ^ ((lane >> 3) & 7);
    int t0 = (s == 0) ? 0 : split;                // first kv tile staged
    const f16_t* kp0 = Kg + (size_t)(t0 * 64 + srow) * Udim + schunk * 8;
    const f16_t* kp1 = kp0 + (size_t)32 * Udim;
    const f16_t* vp0 = Vg + (size_t)srow * Seq + t0 * 64 + schunk * 8;
    const f16_t* vp1 = vp0 + (size_t)32 * Seq;

    int qidxA = qa * 64 + w * 16 + l16;
    int qidxB = qb * 64 + w * 16 + l16;
    const f16_t* QpA = Q + (bS + qidxA) * Udim + h * Dh;
    f16x8 qfA[2], qfB[2];
#pragma unroll
    for (int ss = 0; ss < 2; ss++)
        qfA[ss] = *(const f16x8*)(QpA + ss * 32 + quad * 8);
    if (s == 0) {
        const f16_t* QpB = Q + (bS + qidxB) * Udim + h * Dh;
#pragma unroll
        for (int ss = 0; ss < 2; ss++)
            qfB[ss] = *(const f16x8*)(QpB + ss * 32 + quad * 8);
    }

    // lane-constant swizzled read offsets (f16 elements)
    int m = l16 & 7;
    int kO0 = l16 * 64 + ((quad ^ m) << 3);
    int kO1 = l16 * 64 + (((4 + quad) ^ m) << 3);
    int vO[4];
#pragma unroll
    for (int t = 0; t < 4; t++)
        vO[t] = l16 * 64 + (((t * 32 + quad * 8) ^ (m << 4)) >> 1);

    f32x4 OA[4] = {}, OB[4] = {};
    float lsA = 0.0f, lsB = 0.0f;

    auto STAGE = [&](int nb) AINL {
        gload16(kp0, &Ks[nb][w * 512]);
        gload16(kp1, &Ks[nb][2048 + w * 512]);
        gload16(vp0, &Vs[nb][w * 512]);
        gload16(vp1, &Vs[nb][2048 + w * 512]);
        kp0 += (size_t)64 * Udim; kp1 += (size_t)64 * Udim;
        vp0 += 64; vp1 += 64;
    };

    // full tile: optional A, optional B (shared K/V fragments)
    auto TILE = [&](int buf, bool wA, bool wB) AINL {
        STAGE(buf ^ 1);
        f32x4 stA[4], stB[4];
#pragma unroll
        for (int t = 0; t < 4; t++) {
            f16x8 kf0 = *(const f16x8*)&Ks[buf][kO0 + t * 1024];
            f16x8 kf1 = *(const f16x8*)&Ks[buf][kO1 + t * 1024];
            if (wA) {
                f32x4 a = {};
                a = __builtin_amdgcn_mfma_f32_16x16x32_f16(kf0, qfA[0], a, 0, 0, 0);
                a = __builtin_amdgcn_mfma_f32_16x16x32_f16(kf1, qfA[1], a, 0, 0, 0);
                stA[t] = a;
            }
            if (wB) {
                f32x4 bb = {};
                bb = __builtin_amdgcn_mfma_f32_16x16x32_f16(kf0, qfB[0], bb, 0, 0, 0);
                bb = __builtin_amdgcn_mfma_f32_16x16x32_f16(kf1, qfB[1], bb, 0, 0, 0);
                stB[t] = bb;
            }
        }
        f16x4 pA[4], pB[4];
#pragma unroll
        for (int t = 0; t < 4; t++) {
            if (wA) {
                float p0 = EXP2F(stA[t][0]);
                float p1 = EXP2F(stA[t][1]);
                float p2 = EXP2F(stA[t][2]);
                float p3 = EXP2F(stA[t][3]);
                lsA += (p0 + p1) + (p2 + p3);
                f16x2 lo = pkrtz(p0, p1);
                f16x2 hi = pkrtz(p2, p3);
                pA[t][0] = lo[0]; pA[t][1] = lo[1];
                pA[t][2] = hi[0]; pA[t][3] = hi[1];
            }
            if (wB) {
                float b0 = EXP2F(stB[t][0]);
                float b1 = EXP2F(stB[t][1]);
                float b2 = EXP2F(stB[t][2]);
                float b3 = EXP2F(stB[t][3]);
                lsB += (b0 + b1) + (b2 + b3);
                f16x2 blo = pkrtz(b0, b1);
                f16x2 bhi = pkrtz(b2, b3);
                pB[t][0] = blo[0]; pB[t][1] = blo[1];
                pB[t][2] = bhi[0]; pB[t][3] = bhi[1];
            }
        }
#pragma unroll
        for (int t = 0; t < 4; t++) {
#pragma unroll
            for (int dt = 0; dt < 4; dt++) {
                f16x4 vf = *(const f16x4*)&Vs[buf][vO[t] + dt * 1024];
                if (wA)
                    OA[dt] = __builtin_amdgcn_mfma_f32_16x16x16f16(vf, pA[t], OA[dt], 0, 0, 0);
                if (wB)
                    OB[dt] = __builtin_amdgcn_mfma_f32_16x16x16f16(vf, pB[t], OB[dt], 0, 0, 0);
            }
        }
        __syncthreads();
    };

    // tile t==qb (sub0, split>qb): A full + B causal diagonal
    auto TILE_AdB = [&](int buf) AINL {
        STAGE(buf ^ 1);
        int kv0 = qb * 64;
        f32x4 stA[4];
#pragma unroll
        for (int t = 0; t < 4; t++) {
            f16x8 kf0 = *(const f16x8*)&Ks[buf][kO0 + t * 1024];
            f16x8 kf1 = *(const f16x8*)&Ks[buf][kO1 + t * 1024];
            f32x4 a = {};
            a = __builtin_amdgcn_mfma_f32_16x16x32_f16(kf0, qfA[0], a, 0, 0, 0);
            a = __builtin_amdgcn_mfma_f32_16x16x32_f16(kf1, qfA[1], a, 0, 0, 0);
            stA[t] = a;
            if (t <= w) {
                f32x4 bb = {};
                bb = __builtin_amdgcn_mfma_f32_16x16x32_f16(kf0, qfB[0], bb, 0, 0, 0);
                bb = __builtin_amdgcn_mfma_f32_16x16x32_f16(kf1, qfB[1], bb, 0, 0, 0);
                f16x4 pfd;
#pragma unroll
                for (int rr2 = 0; rr2 < 4; rr2++) {
                    float sv = bb[rr2];
                    if (kv0 + t * 16 + quad * 4 + rr2 > qidxB) sv = -1e30f;
                    float pv = EXP2F(sv);
                    lsB += pv;
                    pfd[rr2] = (f16_t)pv;
                }
#pragma unroll
                for (int dt = 0; dt < 4; dt++) {
                    f16x4 vf = *(const f16x4*)&Vs[buf][vO[t] + dt * 1024];
                    OB[dt] = __builtin_amdgcn_mfma_f32_16x16x16f16(vf, pfd, OB[dt], 0, 0, 0);
                }
            }
        }
        f16x4 pA[4];
#pragma unroll
        for (int t = 0; t < 4; t++) {
            float p0 = EXP2F(stA[t][0]);
            float p1 = EXP2F(stA[t][1]);
            float p2 = EXP2F(stA[t][2]);
            float p3 = EXP2F(stA[t][3]);
            lsA += (p0 + p1) + (p2 + p3);
            f16x2 lo = pkrtz(p0, p1);
            f16x2 hi = pkrtz(p2, p3);
            pA[t][0] = lo[0]; pA[t][1] = lo[1];
            pA[t][2] = hi[0]; pA[t][3] = hi[1];
        }
#pragma unroll
        for (int t = 0; t < 4; t++) {
#pragma unroll
            for (int dt = 0; dt < 4; dt++) {
                f16x4 vf = *(const f16x4*)&Vs[buf][vO[t] + dt * 1024];
                OA[dt] = __builtin_amdgcn_mfma_f32_16x16x16f16(vf, pA[t], OA[dt], 0, 0, 0);
            }
        }
        __syncthreads();
    };

    // B causal diagonal only (sub0, split<=qb). no staging, no barrier.
    auto BDIAG = [&](int buf) AINL {
        int kv0 = qb * 64;
#pragma unroll
        for (int t = 0; t < 4; t++) {
            if (t <= w) {
                f16x8 kf0 = *(const f16x8*)&Ks[buf][kO0 + t * 1024];
                f16x8 kf1 = *(const f16x8*)&Ks[buf][kO1 + t * 1024];
                f32x4 bb = {};
                bb = __builtin_amdgcn_mfma_f32_16x16x32_f16(kf0, qfB[0], bb, 0, 0, 0);
                bb = __builtin_amdgcn_mfma_f32_16x16x32_f16(kf1, qfB[1], bb, 0, 0, 0);
                f16x4 pfd;
#pragma unroll
                for (int rr2 = 0; rr2 < 4; rr2++) {
                    float sv = bb[rr2];
                    if (kv0 + t * 16 + quad * 4 + rr2 > qidxB) sv = -1e30f;
                    float pv = EXP2F(sv);
                    lsB += pv;
                    pfd[rr2] = (f16_t)pv;
                }
#pragma unroll
                for (int dt = 0; dt < 4; dt++) {
                    f16x4 vf = *(const f16x4*)&Vs[buf][vO[t] + dt * 1024];
                    OB[dt] = __builtin_amdgcn_mfma_f32_16x16x16f16(vf, pfd, OB[dt], 0, 0, 0);
                }
            }
        }
    };

    // A causal diagonal (sub1 tail). no staging, no barrier.
    auto DIAG_A = [&](int buf) AINL {
        int kv0 = qa * 64;
#pragma unroll
        for (int t = 0; t < 4; t++) {
            if (t <= w) {
                f16x8 kf0 = *(const f16x8*)&Ks[buf][kO0 + t * 1024];
                f16x8 kf1 = *(const f16x8*)&Ks[buf][kO1 + t * 1024];
                f32x4 a = {};
                a = __builtin_amdgcn_mfma_f32_16x16x32_f16(kf0, qfA[0], a, 0, 0, 0);
                a = __builtin_amdgcn_mfma_f32_16x16x32_f16(kf1, qfA[1], a, 0, 0, 0);
                f16x4 pfd;
#pragma unroll
                for (int rr2 = 0; rr2 < 4; rr2++) {
                    float sv = a[rr2];
                    if (kv0 + t * 16 + quad * 4 + rr2 > qidxA) sv = -1e30f;
                    float pv = EXP2F(sv);
                    lsA += pv;
                    pfd[rr2] = (f16_t)pv;
                }
#pragma unroll
                for (int dt = 0; dt < 4; dt++) {
                    f16x4 vf = *(const f16x4*)&Vs[buf][vO[t] + dt * 1024];
                    OA[dt] = __builtin_amdgcn_mfma_f32_16x16x16f16(vf, pfd, OA[dt], 0, 0, 0);
                }
            }
        }
    };

// run n tiles alternating buffers starting at parity `par` (kept literal)
#define RUNN(n, C0, C1)                                    \
    do {                                                   \
        int _n = (n);                                      \
        if (_n > 0 && par) { C1; _n--; par ^= 1; }         \
        while (_n >= 2) { C0; C1; _n -= 2; }               \
        if (_n > 0) { C0; par ^= 1; }                      \
    } while (0)

    int par = 0;
    STAGE(0);                 // preload first tile (t0) into buf 0
    __syncthreads();

    if (s == 0) {
        int pA = (split < qb) ? split : qb;
        RUNN(pA, TILE(0, true, true), TILE(1, true, true));
        if (split > qb) {     // pi<=7: t=qb has A full + B diag
            if (par) TILE_AdB(1); else TILE_AdB(0);
            par ^= 1;
            RUNN(split - qb - 1, TILE(0, true, false), TILE(1, true, false));
        } else {              // pi>=8: B-only region then B diag
            RUNN(qb - split, TILE(0, false, true), TILE(1, false, true));
            if (par) BDIAG(1); else BDIAG(0);
        }
    } else {
        RUNN(16, TILE(0, true, false), TILE(1, true, false));  // qa-split == 16
        if (par) DIAG_A(1); else DIAG_A(0);                    // par is 0; guarded anyway
    }
#undef RUNN

    float s_acc = 0.0f, ss_acc = 0.0f;

    // ---- B epilogue (sub0 owns B fully)
    if (s == 0) {
        lsB += __shfl_xor(lsB, 16);
        lsB += __shfl_xor(lsB, 32);
        float invB = 1.0f / lsB;
        const float* XpB = X + (bS + qidxB) * Udim + h * Dh;
        bf16_t* RpB = R + (bS + qidxB) * Udim + h * Dh;
#pragma unroll
        for (int dt = 0; dt < 4; dt++) {
            f32x4 xv = *(const f32x4*)(XpB + dt * 16 + quad * 4);
            f32x4 o = OB[dt] * invB + xv;
            bf16x4 ob;
#pragma unroll
            for (int rr2 = 0; rr2 < 4; rr2++) {
                ob[rr2] = (bf16_t)o[rr2];
                s_acc += o[rr2];
                ss_acc += o[rr2] * o[rr2];
            }
            *(bf16x4*)(RpB + dt * 16 + quad * 4) = ob;
        }
    }

    // ---- A partial publish (both subs; sub0 may be zero when split==0)
    lsA += __shfl_xor(lsA, 16);
    lsA += __shfl_xor(lsA, 32);        // full-row partial sum in all lanes
    {
        float* slot = POA + (((size_t)pg * 2 + s) << 12) + ((w * 16 + l16) << 6) + quad * 4;
#pragma unroll
        for (int dt = 0; dt < 4; dt++)
            *(f32x4*)(slot + dt * 16) = OA[dt];
        if (lane < 16)
            PLS[((size_t)pg * 2 + s) * 64 + w * 16 + l16] = lsA;
    }
    __threadfence();
    __syncthreads();
    if (tid == 0) shOld = atomicAdd(&flags[pg], 1);
    __syncthreads();

    // ---- last finisher combines A and finalizes it
    if (shOld == 1) {
        __threadfence();
        const float* os = POA + (((size_t)pg * 2 + (s ^ 1)) << 12) + ((w * 16 + l16) << 6) + quad * 4;
#pragma unroll
        for (int dt = 0; dt < 4; dt++)
            OA[dt] += *(const f32x4*)(os + dt * 16);
        lsA += PLS[((size_t)pg * 2 + (s ^ 1)) * 64 + w * 16 + l16];
        float invA = 1.0f / lsA;
        const float* XpA = X + (bS + qidxA) * Udim + h * Dh;
        bf16_t* RpA = R + (bS + qidxA) * Udim + h * Dh;
#pragma unroll
        for (int dt = 0; dt < 4; dt++) {
            f32x4 xv = *(const f32x4*)(XpA + dt * 16 + quad * 4);
            f32x4 o = OA[dt] * invA + xv;
            bf16x4 ob;
#pragma unroll
            for (int rr2 = 0; rr2 < 4; rr2++) {
                ob[rr2] = (bf16_t)o[rr2];
                s_acc += o[rr2];
                ss_acc += o[rr2] * o[rr2];
            }
            *(bf16x4*)(RpA + dt * 16 + quad * 4) = ob;
        }
    }

    // ---- LN stats reduction (zeros contribute harmlessly)
#pragma unroll
    for (int o = 1; o < 64; o <<= 1) {
        s_acc += __shfl_xor(s_acc, o);
        ss_acc += __shfl_xor(ss_acc, o);
    }
    if (lane == 0) { red[w] = s_acc; red[4 + w] = ss_acc; }
    __syncthreads();
    if (tid == 0) {
        atomicAdd(&stats[b], red[0] + red[1] + red[2] + red[3]);
        atomicAdd(&stats[2 + b], red[4] + red[5] + red[6] + red[7]);
    }
}

// ---------------------------------------------------------------- LN apply
__global__ __launch_bounds__(256)
void ln_norm(const bf16_t* __restrict__ R, const float* __restrict__ gamma,
             const float* __restrict__ beta, const float* __restrict__ stats,
             float* __restrict__ out)
{
    constexpr float invN = 1.0f / (float)PerBatch;
    float mu[2], inv[2];
#pragma unroll
    for (int b = 0; b < 2; b++) {
        float m = stats[b] * invN;
        float var = stats[2 + b] * invN - m * m;
        mu[b] = m;
        inv[b] = rsqrtf(var + 1e-5f);
    }
    int i = blockIdx.x * 256 + threadIdx.x;      // over 8-elem groups, 512K
    int f = i * 8;
    int b = f >> 21;
    int su = f & (PerBatch - 1);
    bf16x8 rv = *(const bf16x8*)(R + f);
    float4 g0 = *(const float4*)(gamma + su);
    float4 g1 = *(const float4*)(gamma + su + 4);
    float4 be0 = *(const float4*)(beta + su);
    float4 be1 = *(const float4*)(beta + su + 4);
    float4 o0, o1;
    o0.x = ((float)rv[0] - mu[b]) * inv[b] * g0.x + be0.x;
    o0.y = ((float)rv[1] - mu[b]) * inv[b] * g0.y + be0.y;
    o0.z = ((float)rv[2] - mu[b]) * inv[b] * g0.z + be0.z;
    o0.w = ((float)rv[3] - mu[b]) * inv[b] * g0.w + be0.w;
    o1.x = ((float)rv[4] - mu[b]) * inv[b] * g1.x + be1.x;
    o1.y = ((float)rv[5] - mu[b]) * inv[b] * g1.y + be1.y;
    o1.z = ((float)rv[6] - mu[b]) * inv[b] * g1.z + be1.z;
    o1.w = ((float)rv[7] - mu[b]) * inv[b] * g1.w + be1.w;
    *(float4*)(out + f) = o0;
    *(float4*)(out + f + 4) = o1;
}

// ---------------------------------------------------------------- launch
extern "C" void kernel_launch(void* const* d_in, const int* in_sizes, int n_in,
                              void* d_out, int out_size, void* d_ws, size_t ws_size,
                              hipStream_t stream)
{
    const float* X     = (const float*)d_in[0];
    const float* Wq    = (const float*)d_in[1];
    const float* bq    = (const float*)d_in[2];
    const float* Wk    = (const float*)d_in[3];
    const float* bk    = (const float*)d_in[4];
    const float* Wv    = (const float*)d_in[5];
    const float* bv    = (const float*)d_in[6];
    const float* gamma = (const float*)d_in[7];
    const float* beta  = (const float*)d_in[8];
    float* out = (float*)d_out;

    char* ws = (char*)d_ws;
    constexpr size_t MB = 1024 * 1024;
    // persistent-through-attn buffers first
    f16_t*  Qb   = (f16_t*)(ws + 0 * MB);       // 8MB
    f16_t*  Kb   = (f16_t*)(ws + 8 * MB);       // 8MB
    f16_t*  Vtb  = (f16_t*)(ws + 16 * MB);      // 8MB
    bf16_t* Rb   = (bf16_t*)(ws + 24 * MB);     // 8MB
    // dead-after-gemm buffers; POA aliases them (attn-only lifetime)
    bf16_t* Xb   = (bf16_t*)(ws + 32 * MB);     // 8MB
    bf16_t* Tq   = (bf16_t*)(ws + 40 * MB);     // 2MB
    bf16_t* Tk   = (bf16_t*)(ws + 42 * MB);     // 2MB
    bf16_t* Tv   = (bf16_t*)(ws + 44 * MB);     // 2MB
    float*  POA  = (float*)(ws + 32 * MB);      // 16MB (aliases Xb/Tq/Tk/Tv + 2MB)
    float*  PLS  = (float*)(ws + 48 * MB);      // 256KB
    int*    flags = (int*)(ws + 48 * MB + 256 * 1024);   // 2KB
    float*  stats = (float*)(ws + 48 * MB + 260 * 1024); // 16B

    prep<<<dim3(16, 16, 4), 256, 0, stream>>>(X, Wq, Wk, Wv, Xb, Tq, Tk, Tv, stats, flags);
    gemm_qkv<<<dim3(8, 32, 3), 256, 0, stream>>>(Xb, Tq, Tk, Tv, bq, bk, bv, Qb, Kb, Vtb);
    attn10<<<dim3(1024), 256, 0, stream>>>(Qb, Kb, Vtb, X, Rb, stats, POA, PLS, flags);
    ln_norm<<<dim3(2048), 256, 0, stream>>>(Rb, gamma, beta, stats, out);
}

// Round 4
// 240.405 us; speedup vs baseline: 1.5614x; 1.5614x over previous
//
#include <hip/hip_runtime.h>
#include <hip/hip_bf16.h>

// Problem: B=2, S=2048, C=U=1024, H=16, dh=64. I/O FP32.
// 4 dispatches: prep (cast X->bf16 + transpose/cast W->bf16 + zero stats),
// QKV GEMM (m97-style staging; Q pre-scaled; V written in a fragment-native
// permuted layout), flash attention (BARRIER-FREE + LDS-FREE: K/V are
// L2-resident (512KB/bh, 4bh/XCD < 4MB); each wave owns one heavy + one
// light 16-row q-strip (uniform work, no tail, no cross-block combine);
// K/V fragments gathered directly from L2 as full cache lines), LN apply.

typedef __bf16 bf16_t;
typedef __bf16 bf16x8 __attribute__((ext_vector_type(8)));
typedef __bf16 bf16x4 __attribute__((ext_vector_type(4)));
typedef _Float16 f16_t;
typedef _Float16 f16x2 __attribute__((ext_vector_type(2)));
typedef _Float16 f16x4 __attribute__((ext_vector_type(4)));
typedef _Float16 f16x8 __attribute__((ext_vector_type(8)));
typedef float f32x4 __attribute__((ext_vector_type(4)));

constexpr int Bsz = 2;
constexpr int Seq = 2048;
constexpr int Cdim = 1024;   // == U
constexpr int Udim = 1024;
constexpr int Hn = 16;
constexpr int Dh = 64;
constexpr int Mrows = Bsz * Seq;          // 4096
constexpr int PerBatch = Seq * Udim;      // 2^21
constexpr float SCLQ = 0.125f * 1.44269504088896340736f;  // /sqrt(dh) * log2e

#if __has_builtin(__builtin_amdgcn_exp2f)
#define EXP2F(x) __builtin_amdgcn_exp2f(x)
#else
#define EXP2F(x) exp2f(x)
#endif

#define AINL __attribute__((always_inline))

// async global->LDS, 16B per lane; LDS dest = wave-uniform base + lane*16
__device__ __forceinline__ void gload16(const void* g, void* l)
{
    __builtin_amdgcn_global_load_lds(
        (const __attribute__((address_space(1))) void*)g,
        (__attribute__((address_space(3))) void*)l, 16, 0, 0);
}

// pack two f32 -> f16x2 via v_cvt_pkrtz (returns __fp16x2; bit-identical)
__device__ __forceinline__ f16x2 pkrtz(float a, float b)
{
    return __builtin_bit_cast(f16x2, __builtin_amdgcn_cvt_pkrtz(a, b));
}

// ---------------------------------------------------------------- prep
__global__ __launch_bounds__(256)
void prep(const float* __restrict__ X,
          const float* __restrict__ Wq, const float* __restrict__ Wk,
          const float* __restrict__ Wv,
          bf16_t* __restrict__ Xb,
          bf16_t* __restrict__ Tq, bf16_t* __restrict__ Tk,
          bf16_t* __restrict__ Tv, float* __restrict__ stats)
{
    int z = blockIdx.z;
    int tid = threadIdx.x;
    if (z < 3) {
        const float* W = (z == 0) ? Wq : (z == 1) ? Wk : Wv;
        bf16_t* T = (z == 0) ? Tq : (z == 1) ? Tk : Tv;
        __shared__ bf16_t t[64][65];
        int x0 = blockIdx.x * 64, y0 = blockIdx.y * 64;
        int tx = tid & 63, ty = tid >> 6;
        for (int i = ty; i < 64; i += 4)
            t[i][tx] = (bf16_t)W[(size_t)(y0 + i) * Cdim + x0 + tx];
        __syncthreads();
        for (int i = ty; i < 64; i += 4)
            T[(size_t)(x0 + i) * Cdim + y0 + tx] = t[tx][i];
    } else {
        int bi = blockIdx.y * 16 + blockIdx.x;          // 0..255
        if (bi == 0 && tid < 4) stats[tid] = 0.0f;
        const float4* Xv = (const float4*)X;
#pragma unroll
        for (int k = 0; k < 16; k++) {
            int i = bi * 4096 + k * 256 + tid;          // 1M float4 total
            float4 v = Xv[i];
            bf16x4 o = { (bf16_t)v.x, (bf16_t)v.y, (bf16_t)v.z, (bf16_t)v.w };
            *(bf16x4*)(Xb + (size_t)i * 4) = o;
        }
    }
}

// ---------------------------------------------------------------- QKV GEMM
// m97 structure: 128x128 tile, BK=32, unpadded LDS, global_load_lds width 16.
// z==0: Q pre-scaled by SCLQ. z==1: K.
// z==2: V -> fragment-native permuted layout:
//   Vp[b][h][tile=s>>6][t=(s>>4)&3][dt=d>>4][l16=d&15][q4=(s>>2)&3][r=s&3]
// so the attention PV fragment load (per (t,dt): lanes (quad,l16)) is a
// fully-contiguous 512B wave read. Store pattern (f16x4 per (mt,nt)) is
// identical to the old layout - only the address map changes.
__global__ __launch_bounds__(256)
void gemm_qkv(const bf16_t* __restrict__ X,
              const bf16_t* __restrict__ Wt0, const bf16_t* __restrict__ Wt1,
              const bf16_t* __restrict__ Wt2,
              const float* __restrict__ b0, const float* __restrict__ b1,
              const float* __restrict__ b2,
              f16_t* __restrict__ O0, f16_t* __restrict__ O1, f16_t* __restrict__ O2v)
{
    int z = blockIdx.z;
    const bf16_t* Wt = (z == 0) ? Wt0 : (z == 1) ? Wt1 : Wt2;
    const float* bias = (z == 0) ? b0 : (z == 1) ? b1 : b2;
    float scl = (z == 0) ? SCLQ : 1.0f;

    constexpr int Kd = 1024, Nd = 1024;
    __shared__ __align__(16) bf16_t As[128 * 32];
    __shared__ __align__(16) bf16_t Bs[128 * 32];

    int tid = threadIdx.x;
    int wave = tid >> 6, lane = tid & 63, quad = lane >> 4, l16 = lane & 15;
    int wm = (wave & 1) * 64, wn = (wave >> 1) * 64;
    int m0 = blockIdx.y * 128, n0 = blockIdx.x * 128;

    f32x4 acc[4][4] = {};

    int e0 = wave * 512 + lane * 8;
    int r0 = e0 >> 5, c0 = e0 & 31;
    int e1 = e0 + 2048;
    int r1 = e1 >> 5, c1 = e1 & 31;
    const bf16_t* Ag = X + (size_t)m0 * Kd;
    const bf16_t* Bg = Wt + (size_t)n0 * Kd;
    bf16_t* AsW0 = As + wave * 512;
    bf16_t* AsW1 = As + 2048 + wave * 512;
    bf16_t* BsW0 = Bs + wave * 512;
    bf16_t* BsW1 = Bs + 2048 + wave * 512;

    for (int k0 = 0; k0 < Kd; k0 += 32) {
        gload16(Ag + (size_t)r0 * Kd + k0 + c0, AsW0);
        gload16(Ag + (size_t)r1 * Kd + k0 + c1, AsW1);
        gload16(Bg + (size_t)r0 * Kd + k0 + c0, BsW0);
        gload16(Bg + (size_t)r1 * Kd + k0 + c1, BsW1);
        __syncthreads();

        bf16x8 af[4], bfr[4];
#pragma unroll
        for (int i = 0; i < 4; i++)
            af[i] = *(const bf16x8*)&As[(wm + i * 16 + l16) * 32 + quad * 8];
#pragma unroll
        for (int i = 0; i < 4; i++)
            bfr[i] = *(const bf16x8*)&Bs[(wn + i * 16 + l16) * 32 + quad * 8];
#pragma unroll
        for (int mt = 0; mt < 4; mt++)
#pragma unroll
            for (int nt = 0; nt < 4; nt++)
                acc[mt][nt] = __builtin_amdgcn_mfma_f32_16x16x32_bf16(
                    af[mt], bfr[nt], acc[mt][nt], 0, 0, 0);
        __syncthreads();
    }

    if (z < 2) {
        f16_t* Og = (z == 0) ? O0 : O1;
#pragma unroll
        for (int nt = 0; nt < 4; nt++) {
            int col = n0 + wn + nt * 16 + l16;
            float bv = bias[col];
#pragma unroll
            for (int mt = 0; mt < 4; mt++) {
                int row = m0 + wm + mt * 16 + quad * 4;
#pragma unroll
                for (int r = 0; r < 4; r++)
                    Og[(size_t)(row + r) * Nd + col] = (f16_t)((acc[mt][nt][r] + bv) * scl);
            }
        }
    } else {
        int bb = m0 >> 11;
#pragma unroll
        for (int nt = 0; nt < 4; nt++) {
            int col = n0 + wn + nt * 16 + l16;
            float bv = bias[col];
            int h = col >> 6, d = col & 63;
            // base for (b,h,dt,l16): head block 2048*64 = 131072 f16
            f16_t* vb = O2v + ((size_t)(bb * Hn + h) << 17)
                            + ((d >> 4) << 8) + ((d & 15) << 4);
#pragma unroll
            for (int mt = 0; mt < 4; mt++) {
                int row = m0 + wm + mt * 16 + quad * 4;
                int s = row & (Seq - 1);
                int off = ((s >> 6) << 12) + (((s >> 4) & 3) << 10) + (((s >> 2) & 3) << 2);
                f16x4 pk;
#pragma unroll
                for (int r = 0; r < 4; r++) pk[r] = (f16_t)(acc[mt][nt][r] + bv);
                *(f16x4*)(vb + off) = pk;
            }
        }
    }
}

// ---------------------------------------------------------------- attention
// Barrier-free, LDS-free. 1024 blocks x 128 threads; each wave owns TWO
// 16-row q-strips of the same (b,h): sHi = 127-p (heavy), sLo = p (light)
// -> per-wave work uniform (~34 tile-units), reduction wave-local, no
// combine, no fences, no __syncthreads in the loop. K fragments gathered
// directly from L2 (16 rows x 64B = full lines); V from the permuted
// layout (512B contiguous per load). One kf/vf set feeds both strips
// while the light strip is active. Offset-free exp2 softmax; per-element
// causal mask only on each strip's diagonal tile.
__global__ __launch_bounds__(128, 2)
void attn11(const f16_t* __restrict__ Q, const f16_t* __restrict__ K,
            const f16_t* __restrict__ Vt, const float* __restrict__ X,
            bf16_t* __restrict__ R, float* __restrict__ stats)
{
    int id = blockIdx.x;
    int c = id & 7;            // XCD slot (4 bh per XCD -> K/V L2-resident)
    int rest = id >> 3;        // 0..127
    int g = rest & 3;
    int pp = rest >> 2;        // 0..31
    int bh = (g << 3) | c;
    int b = bh >> 4, h = bh & 15;

    int tid = threadIdx.x;
    int w = tid >> 6, lane = tid & 63, quad = lane >> 4, l16 = lane & 15;
    int p = pp * 2 + w;        // 0..63
    int sHi = 127 - p;         // heavy strip (rows sHi*16..+15)
    int sLo = p;               // light strip
    int DHi = sHi >> 2;        // diagonal 64-kv tile of each strip
    int DLo = sLo >> 2;        // DLo <= 15 < 16 <= DHi always

    size_t bS = (size_t)b * Seq;
    const f16_t* kbase = K + (bS + l16) * Udim + h * Dh + quad * 8;
    const f16_t* vbase = Vt + ((size_t)(b * Hn + h) << 17) + l16 * 16 + quad * 4;

    int qiH = sHi * 16 + l16;
    int qiL = sLo * 16 + l16;
    const f16_t* QpH = Q + (bS + qiH) * Udim + h * Dh;
    const f16_t* QpL = Q + (bS + qiL) * Udim + h * Dh;
    f16x8 qfH[2], qfL[2];
#pragma unroll
    for (int s2 = 0; s2 < 2; s2++) {
        qfH[s2] = *(const f16x8*)(QpH + s2 * 32 + quad * 8);
        qfL[s2] = *(const f16x8*)(QpL + s2 * 32 + quad * 8);
    }

    f32x4 OH[4] = {}, OL[4] = {};
    float lsH = 0.0f, lsL = 0.0f;

    const f16_t* kt = kbase;
    const f16_t* vtp = vbase;

    // one strip-tile: QK (2 mfma/sub-t) -> exp2 -> PV (4 mfma/sub-t)
    auto STRIP = [&](const f16x8 (&kf)[4][2], const f16x4 (&vf)[4][4],
                     const f16x8 (&qf)[2], f32x4 (&O)[4], float& ls,
                     int qi, int kv0, int tcap, bool msk) AINL {
#pragma unroll
        for (int t = 0; t < 4; t++) {
            if (t <= tcap) {
                f32x4 a = {};
                a = __builtin_amdgcn_mfma_f32_16x16x32_f16(kf[t][0], qf[0], a, 0, 0, 0);
                a = __builtin_amdgcn_mfma_f32_16x16x32_f16(kf[t][1], qf[1], a, 0, 0, 0);
                float pv[4];
#pragma unroll
                for (int r = 0; r < 4; r++) {
                    float sv = a[r];
                    if (msk && (kv0 + t * 16 + quad * 4 + r > qi)) sv = -1e30f;
                    pv[r] = EXP2F(sv);
                    ls += pv[r];
                }
                f16x2 lo = pkrtz(pv[0], pv[1]);
                f16x2 hi = pkrtz(pv[2], pv[3]);
                f16x4 pf;
                pf[0] = lo[0]; pf[1] = lo[1]; pf[2] = hi[0]; pf[3] = hi[1];
#pragma unroll
                for (int dt = 0; dt < 4; dt++)
                    O[dt] = __builtin_amdgcn_mfma_f32_16x16x16f16(vf[t][dt], pf, O[dt], 0, 0, 0);
            }
        }
    };

    // main loop: tiles 0..DHi-1 (hi unmasked; lo active while t64<=DLo)
    for (int t64 = 0; t64 < DHi; t64++) {
        f16x8 kf[4][2];
        f16x4 vf[4][4];
#pragma unroll
        for (int t = 0; t < 4; t++)
#pragma unroll
            for (int s2 = 0; s2 < 2; s2++)
                kf[t][s2] = *(const f16x8*)(kt + (size_t)t * 16 * Udim + s2 * 32);
#pragma unroll
        for (int t = 0; t < 4; t++)
#pragma unroll
            for (int dt = 0; dt < 4; dt++)
                vf[t][dt] = *(const f16x4*)(vtp + t * 1024 + dt * 256);

        int kv0 = t64 << 6;
        STRIP(kf, vf, qfH, OH, lsH, qiH, kv0, 3, false);
        if (t64 < DLo)
            STRIP(kf, vf, qfL, OL, lsL, qiL, kv0, 3, false);
        else if (t64 == DLo)
            STRIP(kf, vf, qfL, OL, lsL, qiL, kv0, sLo & 3, true);

        kt += (size_t)64 * Udim;
        vtp += 4096;
    }
    // hi diagonal tile (masked; sub-t <= sHi&3 only)
    {
        f16x8 kf[4][2];
        f16x4 vf[4][4];
#pragma unroll
        for (int t = 0; t < 4; t++)
#pragma unroll
            for (int s2 = 0; s2 < 2; s2++)
                kf[t][s2] = *(const f16x8*)(kt + (size_t)t * 16 * Udim + s2 * 32);
#pragma unroll
        for (int t = 0; t < 4; t++)
#pragma unroll
            for (int dt = 0; dt < 4; dt++)
                vf[t][dt] = *(const f16x4*)(vtp + t * 1024 + dt * 256);
        STRIP(kf, vf, qfH, OH, lsH, qiH, DHi << 6, sHi & 3, true);
    }

    // ---- epilogues: normalize, residual, LN partial stats (wave-local)
    lsH += __shfl_xor(lsH, 16);
    lsH += __shfl_xor(lsH, 32);
    lsL += __shfl_xor(lsL, 16);
    lsL += __shfl_xor(lsL, 32);
    float invH = 1.0f / lsH;
    float invL = 1.0f / lsL;

    float s_acc = 0.0f, ss_acc = 0.0f;

    const float* XpH = X + (bS + qiH) * Udim + h * Dh;
    bf16_t* RpH = R + (bS + qiH) * Udim + h * Dh;
#pragma unroll
    for (int dt = 0; dt < 4; dt++) {
        f32x4 xv = *(const f32x4*)(XpH + dt * 16 + quad * 4);
        f32x4 o = OH[dt] * invH + xv;
        bf16x4 ob;
#pragma unroll
        for (int r = 0; r < 4; r++) {
            ob[r] = (bf16_t)o[r];
            s_acc += o[r];
            ss_acc += o[r] * o[r];
        }
        *(bf16x4*)(RpH + dt * 16 + quad * 4) = ob;
    }

    const float* XpL = X + (bS + qiL) * Udim + h * Dh;
    bf16_t* RpL = R + (bS + qiL) * Udim + h * Dh;
#pragma unroll
    for (int dt = 0; dt < 4; dt++) {
        f32x4 xv = *(const f32x4*)(XpL + dt * 16 + quad * 4);
        f32x4 o = OL[dt] * invL + xv;
        bf16x4 ob;
#pragma unroll
        for (int r = 0; r < 4; r++) {
            ob[r] = (bf16_t)o[r];
            s_acc += o[r];
            ss_acc += o[r] * o[r];
        }
        *(bf16x4*)(RpL + dt * 16 + quad * 4) = ob;
    }

#pragma unroll
    for (int o = 1; o < 64; o <<= 1) {
        s_acc += __shfl_xor(s_acc, o);
        ss_acc += __shfl_xor(ss_acc, o);
    }
    __shared__ float red[4];
    if (lane == 0) { red[w] = s_acc; red[2 + w] = ss_acc; }
    __syncthreads();
    if (tid == 0) {
        atomicAdd(&stats[b], red[0] + red[1]);
        atomicAdd(&stats[2 + b], red[2] + red[3]);
    }
}

// ---------------------------------------------------------------- LN apply
__global__ __launch_bounds__(256)
void ln_norm(const bf16_t* __restrict__ R, const float* __restrict__ gamma,
             const float* __restrict__ beta, const float* __restrict__ stats,
             float* __restrict__ out)
{
    constexpr float invN = 1.0f / (float)PerBatch;
    float mu[2], inv[2];
#pragma unroll
    for (int b = 0; b < 2; b++) {
        float m = stats[b] * invN;
        float var = stats[2 + b] * invN - m * m;
        mu[b] = m;
        inv[b] = rsqrtf(var + 1e-5f);
    }
    int i = blockIdx.x * 256 + threadIdx.x;      // over 8-elem groups, 512K
    int f = i * 8;
    int b = f >> 21;
    int su = f & (PerBatch - 1);
    bf16x8 rv = *(const bf16x8*)(R + f);
    float4 g0 = *(const float4*)(gamma + su);
    float4 g1 = *(const float4*)(gamma + su + 4);
    float4 be0 = *(const float4*)(beta + su);
    float4 be1 = *(const float4*)(beta + su + 4);
    float4 o0, o1;
    o0.x = ((float)rv[0] - mu[b]) * inv[b] * g0.x + be0.x;
    o0.y = ((float)rv[1] - mu[b]) * inv[b] * g0.y + be0.y;
    o0.z = ((float)rv[2] - mu[b]) * inv[b] * g0.z + be0.z;
    o0.w = ((float)rv[3] - mu[b]) * inv[b] * g0.w + be0.w;
    o1.x = ((float)rv[4] - mu[b]) * inv[b] * g1.x + be1.x;
    o1.y = ((float)rv[5] - mu[b]) * inv[b] * g1.y + be1.y;
    o1.z = ((float)rv[6] - mu[b]) * inv[b] * g1.z + be1.z;
    o1.w = ((float)rv[7] - mu[b]) * inv[b] * g1.w + be1.w;
    *(float4*)(out + f) = o0;
    *(float4*)(out + f + 4) = o1;
}

// ---------------------------------------------------------------- launch
extern "C" void kernel_launch(void* const* d_in, const int* in_sizes, int n_in,
                              void* d_out, int out_size, void* d_ws, size_t ws_size,
                              hipStream_t stream)
{
    const float* X     = (const float*)d_in[0];
    const float* Wq    = (const float*)d_in[1];
    const float* bq    = (const float*)d_in[2];
    const float* Wk    = (const float*)d_in[3];
    const float* bk    = (const float*)d_in[4];
    const float* Wv    = (const float*)d_in[5];
    const float* bv    = (const float*)d_in[6];
    const float* gamma = (const float*)d_in[7];
    const float* beta  = (const float*)d_in[8];
    float* out = (float*)d_out;

    char* ws = (char*)d_ws;
    size_t off = 0;
    auto alloc = [&](size_t bytes) -> void* {
        void* p = ws + off;
        off += (bytes + 255) & ~(size_t)255;
        return p;
    };
    bf16_t* Xb = (bf16_t*)alloc((size_t)Mrows * Cdim * 2);
    bf16_t* Tq = (bf16_t*)alloc((size_t)Cdim * Udim * 2);
    bf16_t* Tk = (bf16_t*)alloc((size_t)Cdim * Udim * 2);
    bf16_t* Tv = (bf16_t*)alloc((size_t)Cdim * Udim * 2);
    f16_t*  Qb = (f16_t*)alloc((size_t)Mrows * Udim * 2);
    f16_t*  Kb = (f16_t*)alloc((size_t)Mrows * Udim * 2);
    f16_t*  Vtb = (f16_t*)alloc((size_t)Mrows * Udim * 2);
    bf16_t* Rb = (bf16_t*)alloc((size_t)Mrows * Udim * 2);
    float*  stats = (float*)alloc(4 * sizeof(float));

    prep<<<dim3(16, 16, 4), 256, 0, stream>>>(X, Wq, Wk, Wv, Xb, Tq, Tk, Tv, stats);
    gemm_qkv<<<dim3(8, 32, 3), 256, 0, stream>>>(Xb, Tq, Tk, Tv, bq, bk, bv, Qb, Kb, Vtb);
    attn11<<<dim3(1024), 128, 0, stream>>>(Qb, Kb, Vtb, X, Rb, stats);
    ln_norm<<<dim3(2048), 256, 0, stream>>>(Rb, gamma, beta, stats, out);
}

// Round 5
// 185.059 us; speedup vs baseline: 2.0284x; 1.2991x over previous
//
#include <hip/hip_runtime.h>
#include <hip/hip_bf16.h>

// Problem: B=2, S=2048, C=U=1024, H=16, dh=64. I/O FP32.
// 4 dispatches: prep, QKV GEMM (m97-style; Q pre-scaled; V -> [b,h,d,s]),
// flash attention (8-wave blocks = two 4-wave groups with independent kv
// streams; pair (qa,qb) kv-split at split=15-pi; INTRA-block additive
// combine through LDS -- no fences, no cross-block traffic; uniform 17
// rounds/block, 16 waves/CU flat), LN apply.

typedef __bf16 bf16_t;
typedef __bf16 bf16x8 __attribute__((ext_vector_type(8)));
typedef __bf16 bf16x4 __attribute__((ext_vector_type(4)));
typedef _Float16 f16_t;
typedef _Float16 f16x2 __attribute__((ext_vector_type(2)));
typedef _Float16 f16x4 __attribute__((ext_vector_type(4)));
typedef _Float16 f16x8 __attribute__((ext_vector_type(8)));
typedef float f32x4 __attribute__((ext_vector_type(4)));

constexpr int Bsz = 2;
constexpr int Seq = 2048;
constexpr int Cdim = 1024;   // == U
constexpr int Udim = 1024;
constexpr int Hn = 16;
constexpr int Dh = 64;
constexpr int Mrows = Bsz * Seq;          // 4096
constexpr int PerBatch = Seq * Udim;      // 2^21
constexpr float SCLQ = 0.125f * 1.44269504088896340736f;  // /sqrt(dh) * log2e

#if __has_builtin(__builtin_amdgcn_exp2f)
#define EXP2F(x) __builtin_amdgcn_exp2f(x)
#else
#define EXP2F(x) exp2f(x)
#endif

#define AINL __attribute__((always_inline))

// async global->LDS, 16B per lane; LDS dest = wave-uniform base + lane*16
__device__ __forceinline__ void gload16(const void* g, void* l)
{
    __builtin_amdgcn_global_load_lds(
        (const __attribute__((address_space(1))) void*)g,
        (__attribute__((address_space(3))) void*)l, 16, 0, 0);
}

// pack two f32 -> f16x2 via v_cvt_pkrtz (returns __fp16x2; bit-identical)
__device__ __forceinline__ f16x2 pkrtz(float a, float b)
{
    return __builtin_bit_cast(f16x2, __builtin_amdgcn_cvt_pkrtz(a, b));
}

// ---------------------------------------------------------------- prep
__global__ __launch_bounds__(256)
void prep(const float* __restrict__ X,
          const float* __restrict__ Wq, const float* __restrict__ Wk,
          const float* __restrict__ Wv,
          bf16_t* __restrict__ Xb,
          bf16_t* __restrict__ Tq, bf16_t* __restrict__ Tk,
          bf16_t* __restrict__ Tv, float* __restrict__ stats)
{
    int z = blockIdx.z;
    int tid = threadIdx.x;
    if (z < 3) {
        const float* W = (z == 0) ? Wq : (z == 1) ? Wk : Wv;
        bf16_t* T = (z == 0) ? Tq : (z == 1) ? Tk : Tv;
        __shared__ bf16_t t[64][65];
        int x0 = blockIdx.x * 64, y0 = blockIdx.y * 64;
        int tx = tid & 63, ty = tid >> 6;
        for (int i = ty; i < 64; i += 4)
            t[i][tx] = (bf16_t)W[(size_t)(y0 + i) * Cdim + x0 + tx];
        __syncthreads();
        for (int i = ty; i < 64; i += 4)
            T[(size_t)(x0 + i) * Cdim + y0 + tx] = t[tx][i];
    } else {
        int bi = blockIdx.y * 16 + blockIdx.x;          // 0..255
        if (bi == 0 && tid < 4) stats[tid] = 0.0f;
        const float4* Xv = (const float4*)X;
#pragma unroll
        for (int k = 0; k < 16; k++) {
            int i = bi * 4096 + k * 256 + tid;          // 1M float4 total
            float4 v = Xv[i];
            bf16x4 o = { (bf16_t)v.x, (bf16_t)v.y, (bf16_t)v.z, (bf16_t)v.w };
            *(bf16x4*)(Xb + (size_t)i * 4) = o;
        }
    }
}

// ---------------------------------------------------------------- QKV GEMM
// m97 structure: 128x128 tile, BK=32, unpadded LDS, global_load_lds width 16.
// z==0: Q pre-scaled by SCLQ. z==1: K. z==2: V -> Vt[b][h][d][s].
__global__ __launch_bounds__(256)
void gemm_qkv(const bf16_t* __restrict__ X,
              const bf16_t* __restrict__ Wt0, const bf16_t* __restrict__ Wt1,
              const bf16_t* __restrict__ Wt2,
              const float* __restrict__ b0, const float* __restrict__ b1,
              const float* __restrict__ b2,
              f16_t* __restrict__ O0, f16_t* __restrict__ O1, f16_t* __restrict__ O2v)
{
    int z = blockIdx.z;
    const bf16_t* Wt = (z == 0) ? Wt0 : (z == 1) ? Wt1 : Wt2;
    const float* bias = (z == 0) ? b0 : (z == 1) ? b1 : b2;
    float scl = (z == 0) ? SCLQ : 1.0f;

    constexpr int Kd = 1024, Nd = 1024;
    __shared__ __align__(16) bf16_t As[128 * 32];
    __shared__ __align__(16) bf16_t Bs[128 * 32];

    int tid = threadIdx.x;
    int wave = tid >> 6, lane = tid & 63, quad = lane >> 4, l16 = lane & 15;
    int wm = (wave & 1) * 64, wn = (wave >> 1) * 64;
    int m0 = blockIdx.y * 128, n0 = blockIdx.x * 128;

    f32x4 acc[4][4] = {};

    int e0 = wave * 512 + lane * 8;
    int r0 = e0 >> 5, c0 = e0 & 31;
    int e1 = e0 + 2048;
    int r1 = e1 >> 5, c1 = e1 & 31;
    const bf16_t* Ag = X + (size_t)m0 * Kd;
    const bf16_t* Bg = Wt + (size_t)n0 * Kd;
    bf16_t* AsW0 = As + wave * 512;
    bf16_t* AsW1 = As + 2048 + wave * 512;
    bf16_t* BsW0 = Bs + wave * 512;
    bf16_t* BsW1 = Bs + 2048 + wave * 512;

    for (int k0 = 0; k0 < Kd; k0 += 32) {
        gload16(Ag + (size_t)r0 * Kd + k0 + c0, AsW0);
        gload16(Ag + (size_t)r1 * Kd + k0 + c1, AsW1);
        gload16(Bg + (size_t)r0 * Kd + k0 + c0, BsW0);
        gload16(Bg + (size_t)r1 * Kd + k0 + c1, BsW1);
        __syncthreads();

        bf16x8 af[4], bfr[4];
#pragma unroll
        for (int i = 0; i < 4; i++)
            af[i] = *(const bf16x8*)&As[(wm + i * 16 + l16) * 32 + quad * 8];
#pragma unroll
        for (int i = 0; i < 4; i++)
            bfr[i] = *(const bf16x8*)&Bs[(wn + i * 16 + l16) * 32 + quad * 8];
#pragma unroll
        for (int mt = 0; mt < 4; mt++)
#pragma unroll
            for (int nt = 0; nt < 4; nt++)
                acc[mt][nt] = __builtin_amdgcn_mfma_f32_16x16x32_bf16(
                    af[mt], bfr[nt], acc[mt][nt], 0, 0, 0);
        __syncthreads();
    }

    if (z < 2) {
        f16_t* Og = (z == 0) ? O0 : O1;
#pragma unroll
        for (int nt = 0; nt < 4; nt++) {
            int col = n0 + wn + nt * 16 + l16;
            float bv = bias[col];
#pragma unroll
            for (int mt = 0; mt < 4; mt++) {
                int row = m0 + wm + mt * 16 + quad * 4;
#pragma unroll
                for (int r = 0; r < 4; r++)
                    Og[(size_t)(row + r) * Nd + col] = (f16_t)((acc[mt][nt][r] + bv) * scl);
            }
        }
    } else {
        int bb = m0 >> 11;
#pragma unroll
        for (int nt = 0; nt < 4; nt++) {
            int col = n0 + wn + nt * 16 + l16;
            float bv = bias[col];
            int h = col >> 6, d = col & 63;
            f16_t* vbase = O2v + (((size_t)(bb * Hn + h) * Dh + d) << 11);
#pragma unroll
            for (int mt = 0; mt < 4; mt++) {
                int row = m0 + wm + mt * 16 + quad * 4;
                int s = row & (Seq - 1);
                f16x4 pk;
#pragma unroll
                for (int r = 0; r < 4; r++) pk[r] = (f16_t)(acc[mt][nt][r] + bv);
                *(f16x4*)(vbase + s) = pk;
            }
        }
    }
}

// ---------------------------------------------------------------- attention
// 512 blocks x 512 threads (8 waves = two 4-wave groups). Block owns pair
// (qa=31-pi, qb=pi); split=15-pi. Group0: B tiles 0..qb then A tiles
// 0..split-1 (16 units). Group1: A tiles split..qa incl diag (17 units).
// Each group: own K/V double-buffer (XOR-swizzled LDS via pre-swizzled
// global_load_lds source), attn8's {stage-next, compute, barrier} round.
// Both groups run exactly 17 rounds (group0 idles round 16) -> uniform
// duration, 16 waves/CU FLAT. A-partials (offset-free softmax => additive)
// combine intra-block through group1's dead LDS region: one __syncthreads,
// no fences. Fused residual + LN stats.
__global__ __launch_bounds__(512, 4)
void attn12(const f16_t* __restrict__ Q, const f16_t* __restrict__ K,
            const f16_t* __restrict__ Vt, const float* __restrict__ X,
            bf16_t* __restrict__ R, float* __restrict__ stats)
{
    int id = blockIdx.x;
    int c = id & 7;            // XCD slot (4 bh per XCD -> K/V L2-resident)
    int rr = id >> 3;          // 0..63
    int g = rr & 3;
    int pi = rr >> 2;          // 0..15
    int bh = (g << 3) | c;
    int b = bh >> 4, h = bh & 15;
    int qa = 31 - pi, qb = pi, split = 15 - pi;

    int tid = threadIdx.x;
    int grp = tid >> 8;              // 0 / 1
    int w = (tid >> 6) & 3;          // wave within group
    int lane = tid & 63, quad = lane >> 4, l16 = lane & 15;
    size_t bS = (size_t)b * Seq;

    // LDS: per group 32KB (K buf0|K buf1|V buf0|V buf1, 8KB each);
    // combine area aliases group1's region (dead after its loop); red at end.
    __shared__ __align__(16) char ldsRaw[65600];
    f16_t* KsBase = (f16_t*)(ldsRaw + grp * 32768);
    f16_t* VsBase = (f16_t*)(ldsRaw + grp * 32768 + 16384);
    float* cmbO   = (float*)(ldsRaw + 32768);   // 16KB: 4 waves x 64 lanes x 16 f32
    float* cmbLS  = (float*)(ldsRaw + 49152);   // 256B: 64 rows
    float* red    = (float*)(ldsRaw + 65536);   // 16 f32

    const f16_t* Kg = K + bS * Udim + h * Dh;
    const f16_t* Vg = Vt + ((size_t)(b * Hn + h)) * Dh * Seq;

    // staging geometry (pre-swizzled global source, rule #21)
    int srow = w * 8 + (lane >> 3);
    int schunk = (lane & 7) ^ ((lane >> 3) & 7);

    int qidxA = qa * 64 + w * 16 + l16;
    int qidxB = qb * 64 + w * 16 + l16;
    const f16_t* QpA = Q + (bS + qidxA) * Udim + h * Dh;
    const f16_t* QpB = Q + (bS + qidxB) * Udim + h * Dh;
    f16x8 qfA[2], qfB[2];
#pragma unroll
    for (int s2 = 0; s2 < 2; s2++) {
        qfA[s2] = *(const f16x8*)(QpA + s2 * 32 + quad * 8);
        qfB[s2] = *(const f16x8*)(QpB + s2 * 32 + quad * 8);
    }

    // lane-constant swizzled read offsets (f16 elements)
    int m = l16 & 7;
    int kO0 = l16 * 64 + ((quad ^ m) << 3);
    int kO1 = l16 * 64 + (((4 + quad) ^ m) << 3);
    int vO[4];
#pragma unroll
    for (int t = 0; t < 4; t++)
        vO[t] = l16 * 64 + (((t * 32 + quad * 8) ^ (m << 4)) >> 1);

    f32x4 OA[4] = {}, OB[4] = {};
    float lsA = 0.0f, lsB = 0.0f;

    // stage kv tile `tl` into buf nb of this group's region
    auto STAGE = [&](int nb, int tl) AINL {
        const f16_t* kp = Kg + (size_t)(tl * 64 + srow) * Udim + schunk * 8;
        const f16_t* vp = Vg + (size_t)srow * Seq + tl * 64 + schunk * 8;
        f16_t* kd = KsBase + nb * 4096;
        f16_t* vd = VsBase + nb * 4096;
        gload16(kp, kd + w * 512);
        gload16(kp + (size_t)32 * Udim, kd + 2048 + w * 512);
        gload16(vp, vd + w * 512);
        gload16(vp + (size_t)32 * Seq, vd + 2048 + w * 512);
    };

    // unmasked 16-row x 64-kv compute
    auto CN = [&](int buf, const f16x8 (&qf)[2], f32x4 (&O)[4], float& ls) AINL {
        const f16_t* Kb = KsBase + buf * 4096;
        const f16_t* Vb = VsBase + buf * 4096;
        f32x4 st[4];
#pragma unroll
        for (int t = 0; t < 4; t++) {
            f16x8 kf0 = *(const f16x8*)&Kb[kO0 + t * 1024];
            f16x8 kf1 = *(const f16x8*)&Kb[kO1 + t * 1024];
            f32x4 a = {};
            a = __builtin_amdgcn_mfma_f32_16x16x32_f16(kf0, qf[0], a, 0, 0, 0);
            a = __builtin_amdgcn_mfma_f32_16x16x32_f16(kf1, qf[1], a, 0, 0, 0);
            st[t] = a;
        }
        f16x4 pf[4];
#pragma unroll
        for (int t = 0; t < 4; t++) {
            float p0 = EXP2F(st[t][0]);
            float p1 = EXP2F(st[t][1]);
            float p2 = EXP2F(st[t][2]);
            float p3 = EXP2F(st[t][3]);
            ls += (p0 + p1) + (p2 + p3);
            f16x2 lo = pkrtz(p0, p1);
            f16x2 hi = pkrtz(p2, p3);
            pf[t][0] = lo[0]; pf[t][1] = lo[1];
            pf[t][2] = hi[0]; pf[t][3] = hi[1];
        }
#pragma unroll
        for (int t = 0; t < 4; t++)
#pragma unroll
            for (int dt = 0; dt < 4; dt++) {
                f16x4 vf = *(const f16x4*)&Vb[vO[t] + dt * 1024];
                O[dt] = __builtin_amdgcn_mfma_f32_16x16x16f16(vf, pf[t], O[dt], 0, 0, 0);
            }
    };

    // masked diagonal compute (sub-t <= w, wave-uniform)
    auto CM = [&](int buf, const f16x8 (&qf)[2], f32x4 (&O)[4], float& ls,
                  int kv0, int qidx) AINL {
        const f16_t* Kb = KsBase + buf * 4096;
        const f16_t* Vb = VsBase + buf * 4096;
#pragma unroll
        for (int t = 0; t < 4; t++) {
            if (t <= w) {
                f16x8 kf0 = *(const f16x8*)&Kb[kO0 + t * 1024];
                f16x8 kf1 = *(const f16x8*)&Kb[kO1 + t * 1024];
                f32x4 a = {};
                a = __builtin_amdgcn_mfma_f32_16x16x32_f16(kf0, qf[0], a, 0, 0, 0);
                a = __builtin_amdgcn_mfma_f32_16x16x32_f16(kf1, qf[1], a, 0, 0, 0);
                f16x4 pfd;
#pragma unroll
                for (int r2 = 0; r2 < 4; r2++) {
                    float sv = a[r2];
                    if (kv0 + t * 16 + quad * 4 + r2 > qidx) sv = -1e30f;  // causal
                    float pv = EXP2F(sv);
                    ls += pv;
                    pfd[r2] = (f16_t)pv;
                }
#pragma unroll
                for (int dt = 0; dt < 4; dt++) {
                    f16x4 vf = *(const f16x4*)&Vb[vO[t] + dt * 1024];
                    O[dt] = __builtin_amdgcn_mfma_f32_16x16x16f16(vf, pfd, O[dt], 0, 0, 0);
                }
            }
        }
    };

    // preload round-0 tile into buf 0
    STAGE(0, (grp == 0) ? 0 : split);
    __syncthreads();

    int r = 0;
    auto ROUND = [&](int buf) AINL {
        if (r < 16) {   // stage next round's tile (round 16 has no successor)
            int rn = r + 1;
            int tl = (grp == 0) ? ((rn <= qb) ? rn : rn - qb - 1) : (split + rn);
            STAGE(buf ^ 1, tl);
        }
        if (grp == 0) {
            if (r < qb)       CN(buf, qfB, OB, lsB);
            else if (r == qb) CM(buf, qfB, OB, lsB, qb * 64, qidxB);
            else if (r < 16)  CN(buf, qfA, OA, lsA);
            // r == 16: idle round (barrier only)
        } else {
            if (r < 16)       CN(buf, qfA, OA, lsA);
            else              CM(buf, qfA, OA, lsA, qa * 64, qidxA);
        }
        __syncthreads();
        r++;
    };

    for (int i = 0; i < 8; i++) { ROUND(0); ROUND(1); }
    ROUND(0);   // round 16

    // ---- A-partial row sums (both groups)
    lsA += __shfl_xor(lsA, 16);
    lsA += __shfl_xor(lsA, 32);

    float s_acc = 0.0f, ss_acc = 0.0f;

    if (grp == 1) {
        // publish A partials into own (dead) LDS region
        float* po = cmbO + w * 1024 + lane * 16;
#pragma unroll
        for (int dt = 0; dt < 4; dt++)
            *(f32x4*)(po + dt * 4) = OA[dt];
        if (lane < 16) cmbLS[w * 16 + l16] = lsA;
    } else {
        // finalize B meanwhile
        lsB += __shfl_xor(lsB, 16);
        lsB += __shfl_xor(lsB, 32);
        float invB = 1.0f / lsB;
        const float* XpB = X + (bS + qidxB) * Udim + h * Dh;
        bf16_t* RpB = R + (bS + qidxB) * Udim + h * Dh;
#pragma unroll
        for (int dt = 0; dt < 4; dt++) {
            f32x4 xv = *(const f32x4*)(XpB + dt * 16 + quad * 4);
            f32x4 o = OB[dt] * invB + xv;
            bf16x4 ob;
#pragma unroll
            for (int r2 = 0; r2 < 4; r2++) {
                ob[r2] = (bf16_t)o[r2];
                s_acc += o[r2];
                ss_acc += o[r2] * o[r2];
            }
            *(bf16x4*)(RpB + dt * 16 + quad * 4) = ob;
        }
    }
    __syncthreads();

    if (grp == 0) {
        // combine + finalize A
        const float* po = cmbO + w * 1024 + lane * 16;
#pragma unroll
        for (int dt = 0; dt < 4; dt++)
            OA[dt] += *(const f32x4*)(po + dt * 4);
        lsA += cmbLS[w * 16 + l16];
        float invA = 1.0f / lsA;
        const float* XpA = X + (bS + qidxA) * Udim + h * Dh;
        bf16_t* RpA = R + (bS + qidxA) * Udim + h * Dh;
#pragma unroll
        for (int dt = 0; dt < 4; dt++) {
            f32x4 xv = *(const f32x4*)(XpA + dt * 16 + quad * 4);
            f32x4 o = OA[dt] * invA + xv;
            bf16x4 ob;
#pragma unroll
            for (int r2 = 0; r2 < 4; r2++) {
                ob[r2] = (bf16_t)o[r2];
                s_acc += o[r2];
                ss_acc += o[r2] * o[r2];
            }
            *(bf16x4*)(RpA + dt * 16 + quad * 4) = ob;
        }
    }

    // ---- LN stats reduction over all 8 waves (group1 contributes zeros)
#pragma unroll
    for (int o = 1; o < 64; o <<= 1) {
        s_acc += __shfl_xor(s_acc, o);
        ss_acc += __shfl_xor(ss_acc, o);
    }
    int w8 = tid >> 6;
    if (lane == 0) { red[w8] = s_acc; red[8 + w8] = ss_acc; }
    __syncthreads();
    if (tid == 0) {
        float s = 0.0f, ss = 0.0f;
#pragma unroll
        for (int i = 0; i < 8; i++) { s += red[i]; ss += red[8 + i]; }
        atomicAdd(&stats[b], s);
        atomicAdd(&stats[2 + b], ss);
    }
}

// ---------------------------------------------------------------- LN apply
__global__ __launch_bounds__(256)
void ln_norm(const bf16_t* __restrict__ R, const float* __restrict__ gamma,
             const float* __restrict__ beta, const float* __restrict__ stats,
             float* __restrict__ out)
{
    constexpr float invN = 1.0f / (float)PerBatch;
    float mu[2], inv[2];
#pragma unroll
    for (int b = 0; b < 2; b++) {
        float m = stats[b] * invN;
        float var = stats[2 + b] * invN - m * m;
        mu[b] = m;
        inv[b] = rsqrtf(var + 1e-5f);
    }
    int i = blockIdx.x * 256 + threadIdx.x;      // over 8-elem groups, 512K
    int f = i * 8;
    int b = f >> 21;
    int su = f & (PerBatch - 1);
    bf16x8 rv = *(const bf16x8*)(R + f);
    float4 g0 = *(const float4*)(gamma + su);
    float4 g1 = *(const float4*)(gamma + su + 4);
    float4 be0 = *(const float4*)(beta + su);
    float4 be1 = *(const float4*)(beta + su + 4);
    float4 o0, o1;
    o0.x = ((float)rv[0] - mu[b]) * inv[b] * g0.x + be0.x;
    o0.y = ((float)rv[1] - mu[b]) * inv[b] * g0.y + be0.y;
    o0.z = ((float)rv[2] - mu[b]) * inv[b] * g0.z + be0.z;
    o0.w = ((float)rv[3] - mu[b]) * inv[b] * g0.w + be0.w;
    o1.x = ((float)rv[4] - mu[b]) * inv[b] * g1.x + be1.x;
    o1.y = ((float)rv[5] - mu[b]) * inv[b] * g1.y + be1.y;
    o1.z = ((float)rv[6] - mu[b]) * inv[b] * g1.z + be1.z;
    o1.w = ((float)rv[7] - mu[b]) * inv[b] * g1.w + be1.w;
    *(float4*)(out + f) = o0;
    *(float4*)(out + f + 4) = o1;
}

// ---------------------------------------------------------------- launch
extern "C" void kernel_launch(void* const* d_in, const int* in_sizes, int n_in,
                              void* d_out, int out_size, void* d_ws, size_t ws_size,
                              hipStream_t stream)
{
    const float* X     = (const float*)d_in[0];
    const float* Wq    = (const float*)d_in[1];
    const float* bq    = (const float*)d_in[2];
    const float* Wk    = (const float*)d_in[3];
    const float* bk    = (const float*)d_in[4];
    const float* Wv    = (const float*)d_in[5];
    const float* bv    = (const float*)d_in[6];
    const float* gamma = (const float*)d_in[7];
    const float* beta  = (const float*)d_in[8];
    float* out = (float*)d_out;

    char* ws = (char*)d_ws;
    size_t off = 0;
    auto alloc = [&](size_t bytes) -> void* {
        void* p = ws + off;
        off += (bytes + 255) & ~(size_t)255;
        return p;
    };
    bf16_t* Xb = (bf16_t*)alloc((size_t)Mrows * Cdim * 2);
    bf16_t* Tq = (bf16_t*)alloc((size_t)Cdim * Udim * 2);
    bf16_t* Tk = (bf16_t*)alloc((size_t)Cdim * Udim * 2);
    bf16_t* Tv = (bf16_t*)alloc((size_t)Cdim * Udim * 2);
    f16_t*  Qb = (f16_t*)alloc((size_t)Mrows * Udim * 2);
    f16_t*  Kb = (f16_t*)alloc((size_t)Mrows * Udim * 2);
    f16_t*  Vtb = (f16_t*)alloc((size_t)Mrows * Udim * 2);
    bf16_t* Rb = (bf16_t*)alloc((size_t)Mrows * Udim * 2);
    float*  stats = (float*)alloc(4 * sizeof(float));

    prep<<<dim3(16, 16, 4), 256, 0, stream>>>(X, Wq, Wk, Wv, Xb, Tq, Tk, Tv, stats);
    gemm_qkv<<<dim3(8, 32, 3), 256, 0, stream>>>(Xb, Tq, Tk, Tv, bq, bk, bv, Qb, Kb, Vtb);
    attn12<<<dim3(512), 512, 0, stream>>>(Qb, Kb, Vtb, X, Rb, stats);
    ln_norm<<<dim3(2048), 256, 0, stream>>>(Rb, gamma, beta, stats, out);
}

// Round 6
// 183.956 us; speedup vs baseline: 2.0405x; 1.0060x over previous
//
#include <hip/hip_runtime.h>
#include <hip/hip_bf16.h>

// Problem: B=2, S=2048, C=U=1024, H=16, dh=64. I/O FP32.
// 4 dispatches: prep, QKV GEMM (m97-style + counted-vmcnt double-buffer
// pipeline), flash attention (8-wave blocks = two 4-wave groups, pair
// (qa,qb) kv-split, intra-block LDS combine; counted-vmcnt rounds: loads
// stay in flight across raw barriers, never drained to 0 in the loop),
// LN apply.

typedef __bf16 bf16_t;
typedef __bf16 bf16x8 __attribute__((ext_vector_type(8)));
typedef __bf16 bf16x4 __attribute__((ext_vector_type(4)));
typedef _Float16 f16_t;
typedef _Float16 f16x2 __attribute__((ext_vector_type(2)));
typedef _Float16 f16x4 __attribute__((ext_vector_type(4)));
typedef _Float16 f16x8 __attribute__((ext_vector_type(8)));
typedef float f32x4 __attribute__((ext_vector_type(4)));

constexpr int Bsz = 2;
constexpr int Seq = 2048;
constexpr int Cdim = 1024;   // == U
constexpr int Udim = 1024;
constexpr int Hn = 16;
constexpr int Dh = 64;
constexpr int Mrows = Bsz * Seq;          // 4096
constexpr int PerBatch = Seq * Udim;      // 2^21
constexpr float SCLQ = 0.125f * 1.44269504088896340736f;  // /sqrt(dh) * log2e

#if __has_builtin(__builtin_amdgcn_exp2f)
#define EXP2F(x) __builtin_amdgcn_exp2f(x)
#else
#define EXP2F(x) exp2f(x)
#endif

#define AINL __attribute__((always_inline))
#define BARRIER() __builtin_amdgcn_s_barrier()
#define SCHEDB() __builtin_amdgcn_sched_barrier(0)
#define WAITV4() asm volatile("s_waitcnt vmcnt(4)" ::: "memory")
#define WAITV0() asm volatile("s_waitcnt vmcnt(0)" ::: "memory")

// async global->LDS, 16B per lane; LDS dest = wave-uniform base + lane*16
__device__ __forceinline__ void gload16(const void* g, void* l)
{
    __builtin_amdgcn_global_load_lds(
        (const __attribute__((address_space(1))) void*)g,
        (__attribute__((address_space(3))) void*)l, 16, 0, 0);
}

// pack two f32 -> f16x2 via v_cvt_pkrtz (returns __fp16x2; bit-identical)
__device__ __forceinline__ f16x2 pkrtz(float a, float b)
{
    return __builtin_bit_cast(f16x2, __builtin_amdgcn_cvt_pkrtz(a, b));
}

// ---------------------------------------------------------------- prep
__global__ __launch_bounds__(256)
void prep(const float* __restrict__ X,
          const float* __restrict__ Wq, const float* __restrict__ Wk,
          const float* __restrict__ Wv,
          bf16_t* __restrict__ Xb,
          bf16_t* __restrict__ Tq, bf16_t* __restrict__ Tk,
          bf16_t* __restrict__ Tv, float* __restrict__ stats)
{
    int z = blockIdx.z;
    int tid = threadIdx.x;
    if (z < 3) {
        const float* W = (z == 0) ? Wq : (z == 1) ? Wk : Wv;
        bf16_t* T = (z == 0) ? Tq : (z == 1) ? Tk : Tv;
        __shared__ bf16_t t[64][65];
        int x0 = blockIdx.x * 64, y0 = blockIdx.y * 64;
        int tx = tid & 63, ty = tid >> 6;
        for (int i = ty; i < 64; i += 4)
            t[i][tx] = (bf16_t)W[(size_t)(y0 + i) * Cdim + x0 + tx];
        __syncthreads();
        for (int i = ty; i < 64; i += 4)
            T[(size_t)(x0 + i) * Cdim + y0 + tx] = t[tx][i];
    } else {
        int bi = blockIdx.y * 16 + blockIdx.x;          // 0..255
        if (bi == 0 && tid < 4) stats[tid] = 0.0f;
        const float4* Xv = (const float4*)X;
#pragma unroll
        for (int k = 0; k < 16; k++) {
            int i = bi * 4096 + k * 256 + tid;          // 1M float4 total
            float4 v = Xv[i];
            bf16x4 o = { (bf16_t)v.x, (bf16_t)v.y, (bf16_t)v.z, (bf16_t)v.w };
            *(bf16x4*)(Xb + (size_t)i * 4) = o;
        }
    }
}

// ---------------------------------------------------------------- QKV GEMM
// 128x128 tile, BK=32, DOUBLE-BUFFERED LDS + counted vmcnt: per K-step
// {barrier; stage next into buf^1; vmcnt(4); barrier; compute buf}. Loads
// for step k+1 stay in flight across both barriers of step k.
// z==0: Q pre-scaled by SCLQ. z==1: K. z==2: V -> Vt[b][h][d][s].
__global__ __launch_bounds__(256)
void gemm_qkv(const bf16_t* __restrict__ X,
              const bf16_t* __restrict__ Wt0, const bf16_t* __restrict__ Wt1,
              const bf16_t* __restrict__ Wt2,
              const float* __restrict__ b0, const float* __restrict__ b1,
              const float* __restrict__ b2,
              f16_t* __restrict__ O0, f16_t* __restrict__ O1, f16_t* __restrict__ O2v)
{
    int z = blockIdx.z;
    const bf16_t* Wt = (z == 0) ? Wt0 : (z == 1) ? Wt1 : Wt2;
    const float* bias = (z == 0) ? b0 : (z == 1) ? b1 : b2;
    float scl = (z == 0) ? SCLQ : 1.0f;

    constexpr int Kd = 1024, Nd = 1024;
    __shared__ __align__(16) bf16_t As[2][4096];
    __shared__ __align__(16) bf16_t Bs[2][4096];

    int tid = threadIdx.x;
    int wave = tid >> 6, lane = tid & 63, quad = lane >> 4, l16 = lane & 15;
    int wm = (wave & 1) * 64, wn = (wave >> 1) * 64;
    int m0 = blockIdx.y * 128, n0 = blockIdx.x * 128;

    f32x4 acc[4][4] = {};

    int e0 = wave * 512 + lane * 8;
    int r0 = e0 >> 5, c0 = e0 & 31;
    int e1 = e0 + 2048;
    int r1 = e1 >> 5, c1 = e1 & 31;
    const bf16_t* Ag = X + (size_t)m0 * Kd;
    const bf16_t* Bg = Wt + (size_t)n0 * Kd;

    auto STG = [&](int nb, int k0) AINL {
        gload16(Ag + (size_t)r0 * Kd + k0 + c0, &As[nb][wave * 512]);
        gload16(Ag + (size_t)r1 * Kd + k0 + c1, &As[nb][2048 + wave * 512]);
        gload16(Bg + (size_t)r0 * Kd + k0 + c0, &Bs[nb][wave * 512]);
        gload16(Bg + (size_t)r1 * Kd + k0 + c1, &Bs[nb][2048 + wave * 512]);
    };

    int kNext = 32;
    auto STEP = [&](int buf, bool doStage) AINL {
        BARRIER();                       // WAR: prev step's readers of buf^1 done
        if (doStage) { STG(buf ^ 1, kNext); kNext += 32; WAITV4(); }
        else WAITV0();
        BARRIER();                       // all waves' current-step loads landed
        SCHEDB();
        bf16x8 af[4], bfr[4];
#pragma unroll
        for (int i = 0; i < 4; i++)
            af[i] = *(const bf16x8*)&As[buf][(wm + i * 16 + l16) * 32 + quad * 8];
#pragma unroll
        for (int i = 0; i < 4; i++)
            bfr[i] = *(const bf16x8*)&Bs[buf][(wn + i * 16 + l16) * 32 + quad * 8];
#pragma unroll
        for (int mt = 0; mt < 4; mt++)
#pragma unroll
            for (int nt = 0; nt < 4; nt++)
                acc[mt][nt] = __builtin_amdgcn_mfma_f32_16x16x32_bf16(
                    af[mt], bfr[nt], acc[mt][nt], 0, 0, 0);
    };

    STG(0, 0);                           // prologue: K-step 0 into buf 0
    for (int it = 0; it < 15; it++) { STEP(0, true); STEP(1, true); }  // steps 0..29
    STEP(0, true);                       // step 30 (stages k=992)
    STEP(1, false);                      // step 31 (no successor)

    if (z < 2) {
        f16_t* Og = (z == 0) ? O0 : O1;
#pragma unroll
        for (int nt = 0; nt < 4; nt++) {
            int col = n0 + wn + nt * 16 + l16;
            float bv = bias[col];
#pragma unroll
            for (int mt = 0; mt < 4; mt++) {
                int row = m0 + wm + mt * 16 + quad * 4;
#pragma unroll
                for (int r = 0; r < 4; r++)
                    Og[(size_t)(row + r) * Nd + col] = (f16_t)((acc[mt][nt][r] + bv) * scl);
            }
        }
    } else {
        int bb = m0 >> 11;
#pragma unroll
        for (int nt = 0; nt < 4; nt++) {
            int col = n0 + wn + nt * 16 + l16;
            float bv = bias[col];
            int h = col >> 6, d = col & 63;
            f16_t* vbase = O2v + (((size_t)(bb * Hn + h) * Dh + d) << 11);
#pragma unroll
            for (int mt = 0; mt < 4; mt++) {
                int row = m0 + wm + mt * 16 + quad * 4;
                int s = row & (Seq - 1);
                f16x4 pk;
#pragma unroll
                for (int r = 0; r < 4; r++) pk[r] = (f16_t)(acc[mt][nt][r] + bv);
                *(f16x4*)(vbase + s) = pk;
            }
        }
    }
}

// ---------------------------------------------------------------- attention
// 512 blocks x 512 threads (8 waves = two 4-wave groups). Block owns pair
// (qa=31-pi, qb=pi); split=15-pi. Group0: B tiles 0..qb then A tiles
// 0..split-1 (16 units). Group1: A tiles split..qa incl diag (17 units).
// Counted-vmcnt rounds: {barrier; STAGE next; vmcnt(4); barrier; compute}.
// Loads for round r+1 stay in flight across round r's barriers — no
// vmcnt(0) drain in the loop (the m218/T4 fix for the ~50% idle seen in
// attn12's counters). A-partials combine intra-block through group1's
// dead LDS region (explicit barrier before reuse). Fused residual+LN stats.
__global__ __launch_bounds__(512, 4)
void attn13(const f16_t* __restrict__ Q, const f16_t* __restrict__ K,
            const f16_t* __restrict__ Vt, const float* __restrict__ X,
            bf16_t* __restrict__ R, float* __restrict__ stats)
{
    int id = blockIdx.x;
    int c = id & 7;            // XCD slot (4 bh per XCD -> K/V L2-resident)
    int rr = id >> 3;          // 0..63
    int g = rr & 3;
    int pi = rr >> 2;          // 0..15
    int bh = (g << 3) | c;
    int b = bh >> 4, h = bh & 15;
    int qa = 31 - pi, qb = pi, split = 15 - pi;

    int tid = threadIdx.x;
    int grp = tid >> 8;              // 0 / 1
    int w = (tid >> 6) & 3;          // wave within group
    int lane = tid & 63, quad = lane >> 4, l16 = lane & 15;
    size_t bS = (size_t)b * Seq;

    // LDS: per group 32KB (K buf0|K buf1|V buf0|V buf1, 8KB each);
    // combine area aliases group1's region (dead after its loop); red at end.
    __shared__ __align__(16) char ldsRaw[65600];
    f16_t* KsBase = (f16_t*)(ldsRaw + grp * 32768);
    f16_t* VsBase = (f16_t*)(ldsRaw + grp * 32768 + 16384);
    float* cmbO   = (float*)(ldsRaw + 32768);   // 16KB: 4 waves x 64 lanes x 16 f32
    float* cmbLS  = (float*)(ldsRaw + 49152);   // 256B: 64 rows
    float* red    = (float*)(ldsRaw + 65536);   // 16 f32

    const f16_t* Kg = K + bS * Udim + h * Dh;
    const f16_t* Vg = Vt + ((size_t)(b * Hn + h)) * Dh * Seq;

    // staging geometry (pre-swizzled global source, rule #21)
    int srow = w * 8 + (lane >> 3);
    int schunk = (lane & 7) ^ ((lane >> 3) & 7);

    int qidxA = qa * 64 + w * 16 + l16;
    int qidxB = qb * 64 + w * 16 + l16;
    const f16_t* QpA = Q + (bS + qidxA) * Udim + h * Dh;
    const f16_t* QpB = Q + (bS + qidxB) * Udim + h * Dh;
    f16x8 qfA[2], qfB[2];
#pragma unroll
    for (int s2 = 0; s2 < 2; s2++) {
        qfA[s2] = *(const f16x8*)(QpA + s2 * 32 + quad * 8);
        qfB[s2] = *(const f16x8*)(QpB + s2 * 32 + quad * 8);
    }

    // lane-constant swizzled read offsets (f16 elements)
    int m = l16 & 7;
    int kO0 = l16 * 64 + ((quad ^ m) << 3);
    int kO1 = l16 * 64 + (((4 + quad) ^ m) << 3);
    int vO[4];
#pragma unroll
    for (int t = 0; t < 4; t++)
        vO[t] = l16 * 64 + (((t * 32 + quad * 8) ^ (m << 4)) >> 1);

    f32x4 OA[4] = {}, OB[4] = {};
    float lsA = 0.0f, lsB = 0.0f;

    // stage kv tile `tl` into buf nb of this group's region (4 loads)
    auto STAGE = [&](int nb, int tl) AINL {
        const f16_t* kp = Kg + (size_t)(tl * 64 + srow) * Udim + schunk * 8;
        const f16_t* vp = Vg + (size_t)srow * Seq + tl * 64 + schunk * 8;
        f16_t* kd = KsBase + nb * 4096;
        f16_t* vd = VsBase + nb * 4096;
        gload16(kp, kd + w * 512);
        gload16(kp + (size_t)32 * Udim, kd + 2048 + w * 512);
        gload16(vp, vd + w * 512);
        gload16(vp + (size_t)32 * Seq, vd + 2048 + w * 512);
    };

    // unmasked 16-row x 64-kv compute
    auto CN = [&](int buf, const f16x8 (&qf)[2], f32x4 (&O)[4], float& ls) AINL {
        const f16_t* Kb = KsBase + buf * 4096;
        const f16_t* Vb = VsBase + buf * 4096;
        f32x4 st[4];
#pragma unroll
        for (int t = 0; t < 4; t++) {
            f16x8 kf0 = *(const f16x8*)&Kb[kO0 + t * 1024];
            f16x8 kf1 = *(const f16x8*)&Kb[kO1 + t * 1024];
            f32x4 a = {};
            a = __builtin_amdgcn_mfma_f32_16x16x32_f16(kf0, qf[0], a, 0, 0, 0);
            a = __builtin_amdgcn_mfma_f32_16x16x32_f16(kf1, qf[1], a, 0, 0, 0);
            st[t] = a;
        }
        f16x4 pf[4];
#pragma unroll
        for (int t = 0; t < 4; t++) {
            float p0 = EXP2F(st[t][0]);
            float p1 = EXP2F(st[t][1]);
            float p2 = EXP2F(st[t][2]);
            float p3 = EXP2F(st[t][3]);
            ls += (p0 + p1) + (p2 + p3);
            f16x2 lo = pkrtz(p0, p1);
            f16x2 hi = pkrtz(p2, p3);
            pf[t][0] = lo[0]; pf[t][1] = lo[1];
            pf[t][2] = hi[0]; pf[t][3] = hi[1];
        }
#pragma unroll
        for (int t = 0; t < 4; t++)
#pragma unroll
            for (int dt = 0; dt < 4; dt++) {
                f16x4 vf = *(const f16x4*)&Vb[vO[t] + dt * 1024];
                O[dt] = __builtin_amdgcn_mfma_f32_16x16x16f16(vf, pf[t], O[dt], 0, 0, 0);
            }
    };

    // masked diagonal compute (sub-t <= w, wave-uniform)
    auto CM = [&](int buf, const f16x8 (&qf)[2], f32x4 (&O)[4], float& ls,
                  int kv0, int qidx) AINL {
        const f16_t* Kb = KsBase + buf * 4096;
        const f16_t* Vb = VsBase + buf * 4096;
#pragma unroll
        for (int t = 0; t < 4; t++) {
            if (t <= w) {
                f16x8 kf0 = *(const f16x8*)&Kb[kO0 + t * 1024];
                f16x8 kf1 = *(const f16x8*)&Kb[kO1 + t * 1024];
                f32x4 a = {};
                a = __builtin_amdgcn_mfma_f32_16x16x32_f16(kf0, qf[0], a, 0, 0, 0);
                a = __builtin_amdgcn_mfma_f32_16x16x32_f16(kf1, qf[1], a, 0, 0, 0);
                f16x4 pfd;
#pragma unroll
                for (int r2 = 0; r2 < 4; r2++) {
                    float sv = a[r2];
                    if (kv0 + t * 16 + quad * 4 + r2 > qidx) sv = -1e30f;  // causal
                    float pv = EXP2F(sv);
                    ls += pv;
                    pfd[r2] = (f16_t)pv;
                }
#pragma unroll
                for (int dt = 0; dt < 4; dt++) {
                    f16x4 vf = *(const f16x4*)&Vb[vO[t] + dt * 1024];
                    O[dt] = __builtin_amdgcn_mfma_f32_16x16x16f16(vf, pfd, O[dt], 0, 0, 0);
                }
            }
        }
    };

    // counted-vmcnt round: loads for r+1 survive across both barriers
    int r = 0;
    auto ROUND = [&](int buf) AINL {
        BARRIER();                       // WAR: prev round's readers of buf^1 done
        if (r < 16) {
            int rn = r + 1;
            int tl = (grp == 0) ? ((rn <= qb) ? rn : rn - qb - 1) : (split + rn);
            STAGE(buf ^ 1, tl);          // issue loads for round r+1
            WAITV4();                    // my round-r loads landed (r+1's in flight)
        } else {
            WAITV0();
        }
        BARRIER();                       // all waves' round-r loads landed
        SCHEDB();
        if (grp == 0) {
            if (r < qb)       CN(buf, qfB, OB, lsB);
            else if (r == qb) CM(buf, qfB, OB, lsB, qb * 64, qidxB);
            else if (r < 16)  CN(buf, qfA, OA, lsA);
            // r == 16: idle round (barriers only)
        } else {
            if (r < 16)       CN(buf, qfA, OA, lsA);
            else              CM(buf, qfA, OA, lsA, qa * 64, qidxA);
        }
        r++;
    };

    STAGE(0, (grp == 0) ? 0 : split);    // prologue: round-0 tile into buf 0
    for (int i = 0; i < 8; i++) { ROUND(0); ROUND(1); }
    ROUND(0);                            // round 16

    BARRIER();   // all LDS reads done before combine area (aliases grp1 bufs)

    // ---- A-partial row sums (both groups)
    lsA += __shfl_xor(lsA, 16);
    lsA += __shfl_xor(lsA, 32);

    float s_acc = 0.0f, ss_acc = 0.0f;

    if (grp == 1) {
        // publish A partials into own (dead) LDS region
        float* po = cmbO + w * 1024 + lane * 16;
#pragma unroll
        for (int dt = 0; dt < 4; dt++)
            *(f32x4*)(po + dt * 4) = OA[dt];
        if (lane < 16) cmbLS[w * 16 + l16] = lsA;
    } else {
        // finalize B meanwhile
        lsB += __shfl_xor(lsB, 16);
        lsB += __shfl_xor(lsB, 32);
        float invB = 1.0f / lsB;
        const float* XpB = X + (bS + qidxB) * Udim + h * Dh;
        bf16_t* RpB = R + (bS + qidxB) * Udim + h * Dh;
#pragma unroll
        for (int dt = 0; dt < 4; dt++) {
            f32x4 xv = *(const f32x4*)(XpB + dt * 16 + quad * 4);
            f32x4 o = OB[dt] * invB + xv;
            bf16x4 ob;
#pragma unroll
            for (int r2 = 0; r2 < 4; r2++) {
                ob[r2] = (bf16_t)o[r2];
                s_acc += o[r2];
                ss_acc += o[r2] * o[r2];
            }
            *(bf16x4*)(RpB + dt * 16 + quad * 4) = ob;
        }
    }
    __syncthreads();

    if (grp == 0) {
        // combine + finalize A
        const float* po = cmbO + w * 1024 + lane * 16;
#pragma unroll
        for (int dt = 0; dt < 4; dt++)
            OA[dt] += *(const f32x4*)(po + dt * 4);
        lsA += cmbLS[w * 16 + l16];
        float invA = 1.0f / lsA;
        const float* XpA = X + (bS + qidxA) * Udim + h * Dh;
        bf16_t* RpA = R + (bS + qidxA) * Udim + h * Dh;
#pragma unroll
        for (int dt = 0; dt < 4; dt++) {
            f32x4 xv = *(const f32x4*)(XpA + dt * 16 + quad * 4);
            f32x4 o = OA[dt] * invA + xv;
            bf16x4 ob;
#pragma unroll
            for (int r2 = 0; r2 < 4; r2++) {
                ob[r2] = (bf16_t)o[r2];
                s_acc += o[r2];
                ss_acc += o[r2] * o[r2];
            }
            *(bf16x4*)(RpA + dt * 16 + quad * 4) = ob;
        }
    }

    // ---- LN stats reduction over all 8 waves (group1 contributes zeros)
#pragma unroll
    for (int o = 1; o < 64; o <<= 1) {
        s_acc += __shfl_xor(s_acc, o);
        ss_acc += __shfl_xor(ss_acc, o);
    }
    int w8 = tid >> 6;
    if (lane == 0) { red[w8] = s_acc; red[8 + w8] = ss_acc; }
    __syncthreads();
    if (tid == 0) {
        float s = 0.0f, ss = 0.0f;
#pragma unroll
        for (int i = 0; i < 8; i++) { s += red[i]; ss += red[8 + i]; }
        atomicAdd(&stats[b], s);
        atomicAdd(&stats[2 + b], ss);
    }
}

// ---------------------------------------------------------------- LN apply
__global__ __launch_bounds__(256)
void ln_norm(const bf16_t* __restrict__ R, const float* __restrict__ gamma,
             const float* __restrict__ beta, const float* __restrict__ stats,
             float* __restrict__ out)
{
    constexpr float invN = 1.0f / (float)PerBatch;
    float mu[2], inv[2];
#pragma unroll
    for (int b = 0; b < 2; b++) {
        float m = stats[b] * invN;
        float var = stats[2 + b] * invN - m * m;
        mu[b] = m;
        inv[b] = rsqrtf(var + 1e-5f);
    }
    int i = blockIdx.x * 256 + threadIdx.x;      // over 8-elem groups, 512K
    int f = i * 8;
    int b = f >> 21;
    int su = f & (PerBatch - 1);
    bf16x8 rv = *(const bf16x8*)(R + f);
    float4 g0 = *(const float4*)(gamma + su);
    float4 g1 = *(const float4*)(gamma + su + 4);
    float4 be0 = *(const float4*)(beta + su);
    float4 be1 = *(const float4*)(beta + su + 4);
    float4 o0, o1;
    o0.x = ((float)rv[0] - mu[b]) * inv[b] * g0.x + be0.x;
    o0.y = ((float)rv[1] - mu[b]) * inv[b] * g0.y + be0.y;
    o0.z = ((float)rv[2] - mu[b]) * inv[b] * g0.z + be0.z;
    o0.w = ((float)rv[3] - mu[b]) * inv[b] * g0.w + be0.w;
    o1.x = ((float)rv[4] - mu[b]) * inv[b] * g1.x + be1.x;
    o1.y = ((float)rv[5] - mu[b]) * inv[b] * g1.y + be1.y;
    o1.z = ((float)rv[6] - mu[b]) * inv[b] * g1.z + be1.z;
    o1.w = ((float)rv[7] - mu[b]) * inv[b] * g1.w + be1.w;
    *(float4*)(out + f) = o0;
    *(float4*)(out + f + 4) = o1;
}

// ---------------------------------------------------------------- launch
extern "C" void kernel_launch(void* const* d_in, const int* in_sizes, int n_in,
                              void* d_out, int out_size, void* d_ws, size_t ws_size,
                              hipStream_t stream)
{
    const float* X     = (const float*)d_in[0];
    const float* Wq    = (const float*)d_in[1];
    const float* bq    = (const float*)d_in[2];
    const float* Wk    = (const float*)d_in[3];
    const float* bk    = (const float*)d_in[4];
    const float* Wv    = (const float*)d_in[5];
    const float* bv    = (const float*)d_in[6];
    const float* gamma = (const float*)d_in[7];
    const float* beta  = (const float*)d_in[8];
    float* out = (float*)d_out;

    char* ws = (char*)d_ws;
    size_t off = 0;
    auto alloc = [&](size_t bytes) -> void* {
        void* p = ws + off;
        off += (bytes + 255) & ~(size_t)255;
        return p;
    };
    bf16_t* Xb = (bf16_t*)alloc((size_t)Mrows * Cdim * 2);
    bf16_t* Tq = (bf16_t*)alloc((size_t)Cdim * Udim * 2);
    bf16_t* Tk = (bf16_t*)alloc((size_t)Cdim * Udim * 2);
    bf16_t* Tv = (bf16_t*)alloc((size_t)Cdim * Udim * 2);
    f16_t*  Qb = (f16_t*)alloc((size_t)Mrows * Udim * 2);
    f16_t*  Kb = (f16_t*)alloc((size_t)Mrows * Udim * 2);
    f16_t*  Vtb = (f16_t*)alloc((size_t)Mrows * Udim * 2);
    bf16_t* Rb = (bf16_t*)alloc((size_t)Mrows * Udim * 2);
    float*  stats = (float*)alloc(4 * sizeof(float));

    prep<<<dim3(16, 16, 4), 256, 0, stream>>>(X, Wq, Wk, Wv, Xb, Tq, Tk, Tv, stats);
    gemm_qkv<<<dim3(8, 32, 3), 256, 0, stream>>>(Xb, Tq, Tk, Tv, bq, bk, bv, Qb, Kb, Vtb);
    attn13<<<dim3(512), 512, 0, stream>>>(Qb, Kb, Vtb, X, Rb, stats);
    ln_norm<<<dim3(2048), 256, 0, stream>>>(Rb, gamma, beta, stats, out);
}